// Round 3
// 336.441 us; speedup vs baseline: 1.0253x; 1.0253x over previous
//
#include <hip/hip_runtime.h>
#include <hip/hip_fp16.h>

// ---------------------------------------------------------------------------
// LinkPredictionGNN: 2x GCNConv (self-loops, sym-norm) + pair MLP head.
//   memset gc -> K1 prep_w UNION hist -> K2 multisplit UNION gemm1(raw)
//   -> K3 bucket_build (+fused gscale) -> K5 agg1 -> K6 gemm2_f16
//   -> K7 agg2 -> K8 gemm_dual_f16 -> K9 pairs
//
// R1/R4: random 4B global writes/atomics -> ~10x line-writeback amp.
// R5: CSR build = 2-level bucket sort, zero global random atomics.
// R6/R7/R14 ALL FAILED (L2-locality for the agg gather): slicing in any
// form regresses. Monolithic agg ~59.5us (~153MB L2-miss @ 2.86TB/s =
// L3 random-256B ceiling) is the floor. Do not retry.
// R12 FAILED: per-edge dinv[src] in the agg loop broke pipelining.
// R15: pairs widened to uint4 lanes, 4 pairs/wave (2KB in flight).
// R16: multisplit overlapped with gemm1 (union dispatch); raw fp16 g +
// row-scale after bucket_build; gcnt/gcur single memset.
// R17: CSR-build path de-latency-ified.
//   - k_bucket_build passes 8-deep manually unrolled (8 loads in flight
//     before the LDS atomics, multisplit_body-style) - was 1 scalar load
//     per vmcnt(0) round-trip, ~32 serial iters, only 98 blocks.
//   - hist in K1: 4-wide dst loads (4 edges/load) + 2-deep unroll.
//   - k_gscale FUSED into k_bucket_build tail (each bucket owns its 512
//     rows + has dinv in regs; coalesced row pass) - kernel removed.
// R18: compile fix - __builtin_nontemporal_load rejects HIP_vector_type
//   int4; use native ext_vector_type(4) int (i32x4).
// R19 (this round): resubmit of R18 - GPU broker timeout, no data.
// R2: fp16 tables (absmax budget ~8e-4 < 1.5e-3 threshold).
// R3: gemm1 (fp32 input) double-bf16-split MFMA (Ah.Bh+Al.Bh+Ah.Bl).
// ---------------------------------------------------------------------------

#define BSH 9                 // log2 nodes per bucket
#define BSZ (1 << BSH)        // 512 nodes per bucket
#define MSB 4096              // edges per multisplit batch/block
#define XPAD 132              // LDS row stride (floats) for fp32 gemm staging
#define HB 256                // hist blocks in fused K1

typedef __attribute__((ext_vector_type(8))) short bf16x8;
typedef __attribute__((ext_vector_type(8))) _Float16 f16x8;
typedef __attribute__((ext_vector_type(4))) float f32x4;
typedef __attribute__((ext_vector_type(4))) int i32x4;

__device__ __forceinline__ void acc8(uint4 u, float4& lo, float4& hi) {
  float2 f0 = __half22float2(((const __half2*)&u)[0]);
  float2 f1 = __half22float2(((const __half2*)&u)[1]);
  float2 f2 = __half22float2(((const __half2*)&u)[2]);
  float2 f3 = __half22float2(((const __half2*)&u)[3]);
  lo.x += f0.x; lo.y += f0.y; lo.z += f1.x; lo.w += f1.y;
  hi.x += f2.x; hi.y += f2.y; hi.z += f3.x; hi.w += f3.y;
}

// Exact fp32 -> bf16 hi/lo split.
__device__ __forceinline__ void split8(const float* v, bf16x8& hi, bf16x8& lo) {
#pragma unroll
  for (int j = 0; j < 8; ++j) {
    unsigned u = __float_as_uint(v[j]);
    hi[j] = (short)(u >> 16);
    float lf = v[j] - __uint_as_float(u & 0xffff0000u);
    lo[j] = (short)(__float_as_uint(lf) >> 16);
  }
}

// K1: weight fragment prep UNION dst bucket-histogram (gc pre-zeroed).
// hist: 4-wide loads (dst is 16B-aligned: offset E*4B, E multiple of 4).
__global__ __launch_bounds__(256) void k_prep_hist(
    const float* __restrict__ W1, const float* __restrict__ W2,
    const float* __restrict__ Wh1, short* __restrict__ fragH,
    short* __restrict__ fragL,
    const int* __restrict__ dst, int* __restrict__ gcnt, int e, int kb) {
  if (blockIdx.x >= 32) {
    __shared__ int h4[512];
    int bid = blockIdx.x - 32;
    int tid = threadIdx.x, wid = tid >> 6;
    for (int t = tid; t < 512; t += 256) h4[t] = 0;
    __syncthreads();
    const i32x4* dst4 = (const i32x4*)dst;
    int ne4 = e >> 2;
    const int STR = HB * 256;
    int i = bid * 256 + tid;
    for (; i < ne4 - STR; i += 2 * STR) {
      i32x4 a = __builtin_nontemporal_load(&dst4[i]);
      i32x4 b = __builtin_nontemporal_load(&dst4[i + STR]);
      atomicAdd(&h4[wid * 128 + (a.x >> BSH)], 1);
      atomicAdd(&h4[wid * 128 + (a.y >> BSH)], 1);
      atomicAdd(&h4[wid * 128 + (a.z >> BSH)], 1);
      atomicAdd(&h4[wid * 128 + (a.w >> BSH)], 1);
      atomicAdd(&h4[wid * 128 + (b.x >> BSH)], 1);
      atomicAdd(&h4[wid * 128 + (b.y >> BSH)], 1);
      atomicAdd(&h4[wid * 128 + (b.z >> BSH)], 1);
      atomicAdd(&h4[wid * 128 + (b.w >> BSH)], 1);
    }
    for (; i < ne4; i += STR) {
      i32x4 a = __builtin_nontemporal_load(&dst4[i]);
      atomicAdd(&h4[wid * 128 + (a.x >> BSH)], 1);
      atomicAdd(&h4[wid * 128 + (a.y >> BSH)], 1);
      atomicAdd(&h4[wid * 128 + (a.z >> BSH)], 1);
      atomicAdd(&h4[wid * 128 + (a.w >> BSH)], 1);
    }
    if (bid == 0 && tid < (e & 3)) {
      int d = dst[(ne4 << 2) + tid];
      atomicAdd(&h4[wid * 128 + (d >> BSH)], 1);
    }
    __syncthreads();
    if (tid < kb)
      atomicAdd(&gcnt[tid], h4[tid] + h4[128 + tid] + h4[256 + tid] + h4[384 + tid]);
    return;
  }
  int g = blockIdx.x * 256 + threadIdx.x;
  int w = g >> 11;
  int rem = g & 2047;
  int lane = rem & 63;
  int ts = rem >> 6;
  int t = ts >> 2, s = ts & 3;
  int n = (t << 4) + (lane & 15);
  int k0 = s * 32 + (lane >> 4) * 8;
  const float* W = (w == 0) ? W1 : (w == 1) ? W2 : (w == 2) ? Wh1 : (Wh1 + 128 * 128);
  short h[8], l[8];
#pragma unroll
  for (int j = 0; j < 8; ++j) {
    float x = W[(k0 + j) * 128 + n];
    if (w == 0) {
      unsigned u = __float_as_uint(x);
      h[j] = (short)(u >> 16);
      float lf = x - __uint_as_float(u & 0xffff0000u);
      l[j] = (short)(__float_as_uint(lf) >> 16);
    } else {
      __half hh = __float2half(x);
      h[j] = __half_as_short(hh);
      l[j] = __half_as_short(__float2half(x - __half2float(hh)));
    }
  }
  ((int4*)fragH)[g] = *(int4*)h;
  ((int4*)fragL)[g] = *(int4*)l;
}

// fp32-input gemm body, NO rowscale (raw fp16 out); sX = 64*XPAD floats LDS.
__device__ __forceinline__ void gemm1_body(
    const float* __restrict__ X, const short* __restrict__ fragH,
    const short* __restrict__ fragL, __half* __restrict__ C16, int n,
    int bid, float* sX) {
  int tid = threadIdx.x;
  int row0 = bid * 64;
  const float2* X2 = (const float2*)(X + (size_t)row0 * 128);
#pragma unroll
  for (int it = 0; it < 16; ++it) {
    int t = it * 256 + tid;
    int r = t >> 6, c2 = t & 63;
    int gr = row0 + r;
    float2 v = (gr < n) ? X2[t] : make_float2(0.f, 0.f);
    *(float2*)&sX[r * XPAD + c2 * 2] = v;
  }
  __syncthreads();
  int wid = tid >> 6, lane = tid & 63;
  int r0 = row0 + wid * 16;
  if (r0 >= n) return;
  int m = lane & 15, quad = lane >> 4;
  const float* xrow = sX + (wid * 16 + m) * XPAD;
  f32x4 acc[8];
#pragma unroll
  for (int t = 0; t < 8; ++t) acc[t] = (f32x4)(0.f);
  const int4* FH = (const int4*)fragH;
  const int4* FL = (const int4*)fragL;
#pragma unroll
  for (int s = 0; s < 4; ++s) {
    int k0 = s * 32 + quad * 8;
    float xv[8];
    *(float2*)&xv[0] = *(const float2*)(xrow + k0);
    *(float2*)&xv[2] = *(const float2*)(xrow + k0 + 2);
    *(float2*)&xv[4] = *(const float2*)(xrow + k0 + 4);
    *(float2*)&xv[6] = *(const float2*)(xrow + k0 + 6);
    bf16x8 ah, al;
    split8(xv, ah, al);
#pragma unroll
    for (int t = 0; t < 8; ++t) {
      int idx = (t * 4 + s) * 64 + lane;
      bf16x8 bh = *(const bf16x8*)&FH[idx];
      bf16x8 bl = *(const bf16x8*)&FL[idx];
      acc[t] = __builtin_amdgcn_mfma_f32_16x16x32_bf16(ah, bh, acc[t], 0, 0, 0);
      acc[t] = __builtin_amdgcn_mfma_f32_16x16x32_bf16(al, bh, acc[t], 0, 0, 0);
      acc[t] = __builtin_amdgcn_mfma_f32_16x16x32_bf16(ah, bl, acc[t], 0, 0, 0);
    }
  }
  // C/D layout: col = lane&15, row = quad*4 + reg   [m89-verified]
#pragma unroll
  for (int t = 0; t < 8; ++t) {
#pragma unroll
    for (int r = 0; r < 4; ++r) {
      int row = r0 + quad * 4 + r;
      C16[(size_t)row * 128 + t * 16 + m] = __float2half(acc[t][r]);
    }
  }
}

// multisplit body: per-wave replicated LDS hist; in-block scan of gcnt; one
// global atomic per bucket per batch. packed = (d_local<<16)|src [src<65536]
// lds = at least 4*128 + 4*128 + 128 + 2 ints.
__device__ __forceinline__ void multisplit_body(
    const int* __restrict__ src, const int* __restrict__ dst,
    const int* __restrict__ gcnt, int* __restrict__ gcur,
    int* __restrict__ tmp, int e, int kb, int bid, int* lds) {
  int* h4 = lds;            // 512
  int* off = lds + 512;     // 512
  int* sbase = lds + 1024;  // 128
  int* ws = lds + 1152;     // 2
  int tid = threadIdx.x, wid = tid >> 6, lane = tid & 63;
  for (int t = tid; t < 512; t += 256) h4[t] = 0;
  __syncthreads();
  int i0 = bid * MSB + tid;
  int d[16], rk[16];
#pragma unroll
  for (int u = 0; u < 16; ++u) {
    int i = i0 + u * 256;
    if (i < e) {
      d[u] = __builtin_nontemporal_load(&dst[i]);
      rk[u] = atomicAdd(&h4[wid * 128 + (d[u] >> BSH)], 1);
    }
  }
  __syncthreads();
  int tot = 0;
  if (tid < 128) {
    int c0 = h4[tid], c1 = h4[128 + tid], c2 = h4[256 + tid], c3 = h4[384 + tid];
    off[tid] = 0; off[128 + tid] = c0;
    off[256 + tid] = c0 + c1; off[384 + tid] = c0 + c1 + c2;
    tot = c0 + c1 + c2 + c3;
  }
  int v = (tid < 128 && tid < kb) ? gcnt[tid] : 0;
  int orig = v;
#pragma unroll
  for (int o = 1; o < 64; o <<= 1) {
    int u = __shfl_up(v, o, 64);
    if (lane >= o) v += u;
  }
  if (lane == 63 && wid < 2) ws[wid] = v;
  __syncthreads();
  if (tid < 128) sbase[tid] = ((wid == 1) ? ws[0] : 0) + v - orig;
  __syncthreads();
  if (tid < kb && tot > 0) sbase[tid] += atomicAdd(&gcur[tid], tot);
  __syncthreads();
#pragma unroll
  for (int u = 0; u < 16; ++u) {
    int i = i0 + u * 256;
    if (i < e) {
      int s = __builtin_nontemporal_load(&src[i]);
      int k = d[u] >> BSH;
      tmp[sbase[k] + off[wid * 128 + k] + rk[u]] = ((d[u] & (BSZ - 1)) << 16) | s;
    }
  }
}

// K2: multisplit UNION gemm1 (both independent: ms needs gcnt/gcur from K1/
// memset; gemm1 needs only W1 frags + x). Overlaps CSR edge pass with GEMM.
__global__ __launch_bounds__(256) void k_ms_gemm1(
    const int* __restrict__ src, const int* __restrict__ dst,
    const int* __restrict__ gcnt, int* __restrict__ gcur,
    int* __restrict__ tmp, int e, int kb, int msblocks,
    const float* __restrict__ X, const short* __restrict__ fragH,
    const short* __restrict__ fragL, __half* __restrict__ C16, int n) {
  __shared__ float sX[64 * XPAD];
  if ((int)blockIdx.x < msblocks) {
    multisplit_body(src, dst, gcnt, gcur, tmp, e, kb, blockIdx.x, (int*)sX);
    return;
  }
  gemm1_body(X, fragH, fragL, C16, n, blockIdx.x - msblocks, sX);
}

// one block per bucket: in-block scan of gcnt; per-node degree + scan +
// cursor scatter in LDS. colarr u16, bucket-local (no write-amp).
// R17: both tmp passes 8-deep unrolled (8 loads in flight before atomics);
// gscale fused into tail (this block owns rows [b*512, b*512+512) of g16).
__global__ __launch_bounds__(512) void k_bucket_build(
    const int* __restrict__ tmp, const int* __restrict__ gcnt,
    int* __restrict__ rowptr, float* __restrict__ dinv,
    unsigned short* __restrict__ colarr, __half* __restrict__ g16,
    int n, int kb, int e) {
  __shared__ int dl[BSZ], cl[BSZ], sbase[128], ws[8];
  __shared__ float sdi[BSZ];
  int t = threadIdx.x, b = blockIdx.x;
  int lane = t & 63, w = t >> 6;
  int v = (t < 128 && t < kb) ? gcnt[t] : 0;
  int orig0 = v;
#pragma unroll
  for (int o = 1; o < 64; o <<= 1) {
    int u = __shfl_up(v, o, 64);
    if (lane >= o) v += u;
  }
  if (lane == 63 && w < 2) ws[w] = v;
  dl[t] = 0;
  __syncthreads();
  if (t < 128) sbase[t] = ((w == 1) ? ws[0] : 0) + v - orig0;
  __syncthreads();
  int s0 = sbase[b];
  int s1 = s0 + gcnt[b];
  // pass 1: per-node degree histogram, 8 loads in flight
  {
    int j = s0 + t;
    for (; j < s1 - 3584; j += 4096) {
      int v0 = tmp[j];
      int v1 = tmp[j + 512];
      int v2 = tmp[j + 1024];
      int v3 = tmp[j + 1536];
      int v4 = tmp[j + 2048];
      int v5 = tmp[j + 2560];
      int v6 = tmp[j + 3072];
      int v7 = tmp[j + 3584];
      atomicAdd(&dl[((unsigned)v0) >> 16], 1);
      atomicAdd(&dl[((unsigned)v1) >> 16], 1);
      atomicAdd(&dl[((unsigned)v2) >> 16], 1);
      atomicAdd(&dl[((unsigned)v3) >> 16], 1);
      atomicAdd(&dl[((unsigned)v4) >> 16], 1);
      atomicAdd(&dl[((unsigned)v5) >> 16], 1);
      atomicAdd(&dl[((unsigned)v6) >> 16], 1);
      atomicAdd(&dl[((unsigned)v7) >> 16], 1);
    }
    for (; j < s1; j += 512)
      atomicAdd(&dl[((unsigned)tmp[j]) >> 16], 1);
  }
  __syncthreads();
  int dv = dl[t], orig = dv;
#pragma unroll
  for (int o = 1; o < 64; o <<= 1) {
    int u = __shfl_up(dv, o, 64);
    if (lane >= o) dv += u;
  }
  if (lane == 63) ws[w] = dv;
  __syncthreads();
  if (t == 0) {
    int a = 0;
#pragma unroll
    for (int k = 0; k < 8; ++k) { int x = ws[k]; ws[k] = a; a += x; }
  }
  __syncthreads();
  int ex = ws[w] + dv - orig;
  cl[t] = ex;
  int node = (b << BSH) + t;
  float di = rsqrtf((float)(orig + 1));  // +1 self loop
  sdi[t] = di;
  if (node < n) {
    rowptr[node] = s0 + ex;
    dinv[node] = di;
  }
  if (b == kb - 1 && t == 0) rowptr[n] = e;
  __syncthreads();
  // pass 2: cursor scatter, 8 loads in flight
  {
    int j = s0 + t;
    for (; j < s1 - 3584; j += 4096) {
      int p0 = tmp[j];
      int p1 = tmp[j + 512];
      int p2 = tmp[j + 1024];
      int p3 = tmp[j + 1536];
      int p4 = tmp[j + 2048];
      int p5 = tmp[j + 2560];
      int p6 = tmp[j + 3072];
      int p7 = tmp[j + 3584];
      int r0 = atomicAdd(&cl[((unsigned)p0) >> 16], 1);
      int r1 = atomicAdd(&cl[((unsigned)p1) >> 16], 1);
      int r2 = atomicAdd(&cl[((unsigned)p2) >> 16], 1);
      int r3 = atomicAdd(&cl[((unsigned)p3) >> 16], 1);
      int r4 = atomicAdd(&cl[((unsigned)p4) >> 16], 1);
      int r5 = atomicAdd(&cl[((unsigned)p5) >> 16], 1);
      int r6 = atomicAdd(&cl[((unsigned)p6) >> 16], 1);
      int r7 = atomicAdd(&cl[((unsigned)p7) >> 16], 1);
      colarr[s0 + r0] = (unsigned short)(p0 & 0xFFFF);
      colarr[s0 + r1] = (unsigned short)(p1 & 0xFFFF);
      colarr[s0 + r2] = (unsigned short)(p2 & 0xFFFF);
      colarr[s0 + r3] = (unsigned short)(p3 & 0xFFFF);
      colarr[s0 + r4] = (unsigned short)(p4 & 0xFFFF);
      colarr[s0 + r5] = (unsigned short)(p5 & 0xFFFF);
      colarr[s0 + r6] = (unsigned short)(p6 & 0xFFFF);
      colarr[s0 + r7] = (unsigned short)(p7 & 0xFFFF);
    }
    for (; j < s1; j += 512) {
      int p = tmp[j];
      int r = atomicAdd(&cl[((unsigned)p) >> 16], 1);
      colarr[s0 + r] = (unsigned short)(p & 0xFFFF);
    }
  }
  // fused gscale (was K4): scale this bucket's rows of g16 by dinv.
  // coalesced: 16 consecutive lanes = one 256B row.
  {
    int base = b << BSH;
    int rows = n - base;
    if (rows > BSZ) rows = BSZ;
    uint4* G = (uint4*)g16;
    for (int idx = t; idx < rows * 16; idx += 512) {
      int rl = idx >> 4;
      float dsc = sdi[rl];
      size_t gi = (size_t)(base + rl) * 16 + (idx & 15);
      uint4 u = G[gi];
      __half2* hp = (__half2*)&u;
#pragma unroll
      for (int k2 = 0; k2 < 4; ++k2) {
        float2 f = __half22float2(hp[k2]);
        hp[k2] = __floats2half2_rn(f.x * dsc, f.y * dsc);
      }
      G[gi] = u;
    }
  }
}

// f16-input GEMM: C16 = fp16(rowscale * X16 @ W), A fp16-exact, B f16 hi+lo.
__global__ __launch_bounds__(256) void k_gemm_f16(
    const __half* __restrict__ X16, const short* __restrict__ fragH,
    const short* __restrict__ fragL, const float* __restrict__ rowscale,
    __half* __restrict__ C16, int n) {
  int wid = threadIdx.x >> 6, lane = threadIdx.x & 63;
  int r0 = (blockIdx.x * 4 + wid) * 16;
  if (r0 >= n) return;
  int m = lane & 15, quad = lane >> 4;
  const uint4* Xr = (const uint4*)(X16 + (size_t)(r0 + m) * 128);
  f32x4 acc[8];
#pragma unroll
  for (int t = 0; t < 8; ++t) acc[t] = (f32x4)(0.f);
  const int4* FH = (const int4*)fragH;
  const int4* FL = (const int4*)fragL;
#pragma unroll
  for (int s = 0; s < 4; ++s) {
    uint4 av = Xr[quad + 4 * s];
    f16x8 a = *(const f16x8*)&av;
#pragma unroll
    for (int t = 0; t < 8; ++t) {
      int idx = (t * 4 + s) * 64 + lane;
      int4 bhv = FH[idx], blv = FL[idx];
      f16x8 bh = *(const f16x8*)&bhv;
      f16x8 bl = *(const f16x8*)&blv;
      acc[t] = __builtin_amdgcn_mfma_f32_16x16x32_f16(a, bh, acc[t], 0, 0, 0);
      acc[t] = __builtin_amdgcn_mfma_f32_16x16x32_f16(a, bl, acc[t], 0, 0, 0);
    }
  }
  float sc[4];
#pragma unroll
  for (int r = 0; r < 4; ++r)
    sc[r] = rowscale ? rowscale[r0 + quad * 4 + r] : 1.f;
#pragma unroll
  for (int t = 0; t < 8; ++t) {
#pragma unroll
    for (int r = 0; r < 4; ++r) {
      int row = r0 + quad * 4 + r;
      C16[(size_t)row * 128 + t * 16 + m] = __float2half(acc[t][r] * sc[r]);
    }
  }
}

// Dual-output f16 GEMM for the head (reads X16 once; no rowscale).
__global__ __launch_bounds__(256) void k_gemm_dual_f16(
    const __half* __restrict__ X16,
    const short* __restrict__ fHa, const short* __restrict__ fLa,
    const short* __restrict__ fHb, const short* __restrict__ fLb,
    __half* __restrict__ A16, __half* __restrict__ B16, int n) {
  int wid = threadIdx.x >> 6, lane = threadIdx.x & 63;
  int r0 = (blockIdx.x * 4 + wid) * 16;
  if (r0 >= n) return;
  int m = lane & 15, quad = lane >> 4;
  const uint4* Xr = (const uint4*)(X16 + (size_t)(r0 + m) * 128);
  f32x4 accA[8], accB[8];
#pragma unroll
  for (int t = 0; t < 8; ++t) { accA[t] = (f32x4)(0.f); accB[t] = (f32x4)(0.f); }
  const int4* FHa = (const int4*)fHa; const int4* FLa = (const int4*)fLa;
  const int4* FHb = (const int4*)fHb; const int4* FLb = (const int4*)fLb;
#pragma unroll
  for (int s = 0; s < 4; ++s) {
    uint4 av = Xr[quad + 4 * s];
    f16x8 a = *(const f16x8*)&av;
#pragma unroll
    for (int t = 0; t < 8; ++t) {
      int idx = (t * 4 + s) * 64 + lane;
      int4 v0 = FHa[idx], v1 = FLa[idx], v2 = FHb[idx], v3 = FLb[idx];
      accA[t] = __builtin_amdgcn_mfma_f32_16x16x32_f16(a, *(const f16x8*)&v0, accA[t], 0, 0, 0);
      accA[t] = __builtin_amdgcn_mfma_f32_16x16x32_f16(a, *(const f16x8*)&v1, accA[t], 0, 0, 0);
      accB[t] = __builtin_amdgcn_mfma_f32_16x16x32_f16(a, *(const f16x8*)&v2, accB[t], 0, 0, 0);
      accB[t] = __builtin_amdgcn_mfma_f32_16x16x32_f16(a, *(const f16x8*)&v3, accB[t], 0, 0, 0);
    }
  }
#pragma unroll
  for (int t = 0; t < 8; ++t) {
#pragma unroll
    for (int r = 0; r < 4; ++r) {
      int row = r0 + quad * 4 + r;
      A16[(size_t)row * 128 + t * 16 + m] = __float2half(accA[t][r]);
      B16[(size_t)row * 128 + t * 16 + m] = __float2half(accB[t][r]);
    }
  }
}

// out16[i,:] = fp16(relu(dinv[i] * (g[i,:] + sum g[col[e],:]) + bias))
// R13 known-good monolithic gather: uint4 lanes, 4 edge subgroups, 4-deep
// unroll = 16 edges in flight. DO NOT slice (R6/R7/R14 all regressed).
__global__ __launch_bounds__(256) void k_agg_h(
    const __half2* __restrict__ g2, const float* __restrict__ dinv,
    const int* __restrict__ rowptr, const unsigned short* __restrict__ col,
    const float* __restrict__ bias, __half* __restrict__ out16, int n) {
  int i = blockIdx.x * 4 + (threadIdx.x >> 6);
  if (i >= n) return;
  int lane = threadIdx.x & 63;
  int sub = lane >> 4;
  int c8 = lane & 15;
  const uint4* G = (const uint4*)g2;
  float4 z = make_float4(0.f, 0.f, 0.f, 0.f);
  float4 lo0 = z, lo1 = z, lo2 = z, lo3 = z, hi0 = z, hi1 = z, hi2 = z, hi3 = z;
  if (sub == 0) acc8(G[(size_t)i * 16 + c8], lo0, hi0);  // self loop once
  int beg = rowptr[i], end = rowptr[i + 1];
  int j = beg;
  for (; j + 16 <= end; j += 16) {
    int s0 = __builtin_nontemporal_load(&col[j + sub]);
    int s1 = __builtin_nontemporal_load(&col[j + 4 + sub]);
    int s2 = __builtin_nontemporal_load(&col[j + 8 + sub]);
    int s3 = __builtin_nontemporal_load(&col[j + 12 + sub]);
    uint4 u0 = G[(size_t)s0 * 16 + c8];
    uint4 u1 = G[(size_t)s1 * 16 + c8];
    uint4 u2 = G[(size_t)s2 * 16 + c8];
    uint4 u3 = G[(size_t)s3 * 16 + c8];
    acc8(u0, lo0, hi0); acc8(u1, lo1, hi1);
    acc8(u2, lo2, hi2); acc8(u3, lo3, hi3);
  }
  for (; j + 4 <= end; j += 4) {
    int s0 = __builtin_nontemporal_load(&col[j + sub]);
    acc8(G[(size_t)s0 * 16 + c8], lo1, hi1);
  }
  int rem = end - j;
  if (sub < rem) {
    int s0 = __builtin_nontemporal_load(&col[j + sub]);
    acc8(G[(size_t)s0 * 16 + c8], lo2, hi2);
  }
  float4 lo, hi;
  lo.x = (lo0.x + lo1.x) + (lo2.x + lo3.x);
  lo.y = (lo0.y + lo1.y) + (lo2.y + lo3.y);
  lo.z = (lo0.z + lo1.z) + (lo2.z + lo3.z);
  lo.w = (lo0.w + lo1.w) + (lo2.w + lo3.w);
  hi.x = (hi0.x + hi1.x) + (hi2.x + hi3.x);
  hi.y = (hi0.y + hi1.y) + (hi2.y + hi3.y);
  hi.z = (hi0.z + hi1.z) + (hi2.z + hi3.z);
  hi.w = (hi0.w + hi1.w) + (hi2.w + hi3.w);
  lo.x += __shfl_down(lo.x, 32, 64); lo.x += __shfl_down(lo.x, 16, 64);
  lo.y += __shfl_down(lo.y, 32, 64); lo.y += __shfl_down(lo.y, 16, 64);
  lo.z += __shfl_down(lo.z, 32, 64); lo.z += __shfl_down(lo.z, 16, 64);
  lo.w += __shfl_down(lo.w, 32, 64); lo.w += __shfl_down(lo.w, 16, 64);
  hi.x += __shfl_down(hi.x, 32, 64); hi.x += __shfl_down(hi.x, 16, 64);
  hi.y += __shfl_down(hi.y, 32, 64); hi.y += __shfl_down(hi.y, 16, 64);
  hi.z += __shfl_down(hi.z, 32, 64); hi.z += __shfl_down(hi.z, 16, 64);
  hi.w += __shfl_down(hi.w, 32, 64); hi.w += __shfl_down(hi.w, 16, 64);
  if (sub == 0) {
    float di = dinv[i];
    float4 b0 = ((const float4*)bias)[2 * c8];
    float4 b1 = ((const float4*)bias)[2 * c8 + 1];
    __half2 q0 = __floats2half2_rn(fmaxf(fmaf(di, lo.x, b0.x), 0.f),
                                   fmaxf(fmaf(di, lo.y, b0.y), 0.f));
    __half2 q1 = __floats2half2_rn(fmaxf(fmaf(di, lo.z, b0.z), 0.f),
                                   fmaxf(fmaf(di, lo.w, b0.w), 0.f));
    __half2 q2 = __floats2half2_rn(fmaxf(fmaf(di, hi.x, b1.x), 0.f),
                                   fmaxf(fmaf(di, hi.y, b1.y), 0.f));
    __half2 q3 = __floats2half2_rn(fmaxf(fmaf(di, hi.z, b1.z), 0.f),
                                   fmaxf(fmaf(di, hi.w, b1.w), 0.f));
    uint4 o;
    o.x = *(unsigned*)&q0; o.y = *(unsigned*)&q1;
    o.z = *(unsigned*)&q2; o.w = *(unsigned*)&q3;
    ((uint4*)out16)[(size_t)i * 16 + c8] = o;
  }
}

// pairs: 4 pairs per wave (R15). uint4 lanes: 16 lanes x 16B = 256B row.
__global__ __launch_bounds__(256) void k_pairs_h(
    const __half* __restrict__ A, const __half* __restrict__ B,
    const int* __restrict__ pairs, const float* __restrict__ bh1,
    const float* __restrict__ wh2, const float* __restrict__ bh2,
    float* __restrict__ out, int P) {
  int wp = (blockIdx.x * 4 + (threadIdx.x >> 6)) * 4;
  int lane = threadIdx.x & 63;
  int sub = lane >> 4;
  int c8 = lane & 15;
  int pr = sub >> 1;
  int ab = sub & 1;
  const uint4* T = ab ? (const uint4*)B : (const uint4*)A;
  int pA = wp + pr;
  int pB = wp + 2 + pr;
  uint4 u0 = make_uint4(0, 0, 0, 0), u1 = u0;
  if (pA < P) {
    int r = pairs[2 * pA + ab];
    u0 = T[(size_t)r * 16 + c8];
  }
  if (pB < P) {
    int r = pairs[2 * pB + ab];
    u1 = T[(size_t)r * 16 + c8];
  }
  float4 b0 = ((const float4*)bh1)[2 * c8];
  float4 b1 = ((const float4*)bh1)[2 * c8 + 1];
  float4 w0 = ((const float4*)wh2)[2 * c8];
  float4 w1 = ((const float4*)wh2)[2 * c8 + 1];
  float s0, s1;
  {
    float4 lo = make_float4(0, 0, 0, 0), hi = lo;
    acc8(u0, lo, hi);
    lo.x += __shfl_down(lo.x, 16, 64); lo.y += __shfl_down(lo.y, 16, 64);
    lo.z += __shfl_down(lo.z, 16, 64); lo.w += __shfl_down(lo.w, 16, 64);
    hi.x += __shfl_down(hi.x, 16, 64); hi.y += __shfl_down(hi.y, 16, 64);
    hi.z += __shfl_down(hi.z, 16, 64); hi.w += __shfl_down(hi.w, 16, 64);
    s0 = fmaxf(lo.x + b0.x, 0.f) * w0.x + fmaxf(lo.y + b0.y, 0.f) * w0.y +
         fmaxf(lo.z + b0.z, 0.f) * w0.z + fmaxf(lo.w + b0.w, 0.f) * w0.w +
         fmaxf(hi.x + b1.x, 0.f) * w1.x + fmaxf(hi.y + b1.y, 0.f) * w1.y +
         fmaxf(hi.z + b1.z, 0.f) * w1.z + fmaxf(hi.w + b1.w, 0.f) * w1.w;
  }
  {
    float4 lo = make_float4(0, 0, 0, 0), hi = lo;
    acc8(u1, lo, hi);
    lo.x += __shfl_down(lo.x, 16, 64); lo.y += __shfl_down(lo.y, 16, 64);
    lo.z += __shfl_down(lo.z, 16, 64); lo.w += __shfl_down(lo.w, 16, 64);
    hi.x += __shfl_down(hi.x, 16, 64); hi.y += __shfl_down(hi.y, 16, 64);
    hi.z += __shfl_down(hi.z, 16, 64); hi.w += __shfl_down(hi.w, 16, 64);
    s1 = fmaxf(lo.x + b0.x, 0.f) * w0.x + fmaxf(lo.y + b0.y, 0.f) * w0.y +
         fmaxf(lo.z + b0.z, 0.f) * w0.z + fmaxf(lo.w + b0.w, 0.f) * w0.w +
         fmaxf(hi.x + b1.x, 0.f) * w1.x + fmaxf(hi.y + b1.y, 0.f) * w1.y +
         fmaxf(hi.z + b1.z, 0.f) * w1.z + fmaxf(hi.w + b1.w, 0.f) * w1.w;
  }
#pragma unroll
  for (int o = 8; o > 0; o >>= 1) {
    s0 += __shfl_down(s0, o, 64);
    s1 += __shfl_down(s1, o, 64);
  }
  float bb = bh2[0];
  if (lane == 0 && wp < P) out[wp] = s0 + bb;
  if (lane == 32 && wp + 1 < P) out[wp + 1] = s0 + bb;
  if (lane == 0 && wp + 2 < P) out[wp + 2] = s1 + bb;
  if (lane == 32 && wp + 3 < P) out[wp + 3] = s1 + bb;
}

extern "C" void kernel_launch(void* const* d_in, const int* in_sizes, int n_in,
                              void* d_out, int out_size, void* d_ws, size_t ws_size,
                              hipStream_t stream) {
  const float* x   = (const float*)d_in[0];
  const int* ei    = (const int*)d_in[1];
  const int* pairs = (const int*)d_in[2];
  const float* W1  = (const float*)d_in[3];
  const float* b1  = (const float*)d_in[4];
  const float* W2  = (const float*)d_in[5];
  const float* b2  = (const float*)d_in[6];
  const float* Wh1 = (const float*)d_in[7];
  const float* bh1 = (const float*)d_in[8];
  const float* Wh2 = (const float*)d_in[9];
  const float* bh2 = (const float*)d_in[10];
  (void)n_in; (void)out_size; (void)ws_size;

  int N = in_sizes[0] / 128;
  int E = in_sizes[1] / 2;
  int P = in_sizes[2] / 2;
  const int* src = ei;
  const int* dst = ei + E;
  int KB = (N + BSZ - 1) >> BSH;  // buckets (98 for N=50000)

  char* wsp = (char*)d_ws;
  size_t off = 0;
  auto alloc = [&](size_t bytes) -> void* {
    void* p = wsp + off;
    off += (bytes + 255) & ~(size_t)255;
    return p;
  };
  __half* g16 = (__half*)alloc((size_t)N * 128 * 2);  // messages; reused as A16
  __half* h1  = (__half*)alloc((size_t)N * 128 * 2);  // fp16; reused as B16
  __half* h2  = (__half*)alloc((size_t)N * 128 * 2);  // fp16
  float* dinv = (float*)alloc((size_t)N * 4);
  int* rowptr = (int*)alloc((size_t)(N + 1) * 4);
  unsigned short* colarr = (unsigned short*)alloc((size_t)E * 2);
  int* tmp    = (int*)alloc((size_t)E * 4);
  short* fragH = (short*)alloc(4 * 2048 * 8 * 2);     // 128KB
  short* fragL = (short*)alloc(4 * 2048 * 8 * 2);     // 128KB
  int* gc     = (int*)alloc(2 * 128 * 4);             // [0:128) gcnt, [128:256) gcur
  int* gcnt = gc;
  int* gcur = gc + 128;
  __half* A16 = g16;            // g16 dead by the time head runs
  __half* B16 = h1;             // h1 dead after conv2 gemm
  short* fH_W1 = fragH + 0 * 16384;  short* fL_W1 = fragL + 0 * 16384;
  short* fH_W2 = fragH + 1 * 16384;  short* fL_W2 = fragL + 1 * 16384;
  short* fH_Wa = fragH + 2 * 16384;  short* fL_Wa = fragL + 2 * 16384;
  short* fH_Wb = fragH + 3 * 16384;  short* fL_Wb = fragL + 3 * 16384;

  int GB = (N + 63) / 64;          // fp32 gemm: 64 rows per block
  int GF = (N / 16 + 3) / 4;       // f16 gemm: 16 rows/wave, 4 waves/block
  int AB = (N + 3) / 4;            // agg: 4 rows per block
  int MS = (E + MSB - 1) / MSB;    // multisplit blocks

  // one memset for both counter arrays, then fused prep+hist
  hipMemsetAsync(gc, 0, 2 * 128 * 4, stream);
  k_prep_hist<<<32 + HB, 256, 0, stream>>>(W1, W2, Wh1, fragH, fragL,
                                           dst, gcnt, E, KB);
  // K2: multisplit UNION gemm1 (raw, unscaled)
  k_ms_gemm1<<<MS + GB, 256, 0, stream>>>(src, dst, gcnt, gcur, tmp, E, KB, MS,
                                          x, fH_W1, fL_W1, g16, N);
  // K3: per-bucket LDS sort -> rowptr/dinv/colarr, then fused g16 row-scale
  k_bucket_build<<<KB, 512, 0, stream>>>(tmp, gcnt, rowptr, dinv, colarr,
                                         g16, N, KB, E);
  // conv1 agg
  k_agg_h<<<AB, 256, 0, stream>>>((const __half2*)g16, dinv, rowptr, colarr, b1, h1, N);
  // conv2 (f16 path)
  k_gemm_f16<<<GF, 256, 0, stream>>>(h1, fH_W2, fL_W2, dinv, g16, N);
  k_agg_h<<<AB, 256, 0, stream>>>((const __half2*)g16, dinv, rowptr, colarr, b2, h2, N);
  // head
  k_gemm_dual_f16<<<GF, 256, 0, stream>>>(h2, fH_Wa, fL_Wa, fH_Wb, fL_Wb,
                                          A16, B16, N);
  k_pairs_h<<<(P + 15) / 16, 256, 0, stream>>>(A16, B16, pairs, bh1, Wh2, bh2,
                                               (float*)d_out, P);
}

// Round 4
// 333.153 us; speedup vs baseline: 1.0354x; 1.0099x over previous
//
#include <hip/hip_runtime.h>
#include <hip/hip_fp16.h>

// ---------------------------------------------------------------------------
// LinkPredictionGNN: 2x GCNConv (self-loops, sym-norm) + pair MLP head.
//   memset gc -> K1 prep_w UNION hist -> K2 multisplit UNION gemm1(raw)
//   -> K3 bucket_build (+fused gscale) -> K5 agg1 -> K6 gemm2_f16
//   -> K7 agg2 -> K8 pairs_mfma (fused dual-gemm + pair head)
//
// R1/R4: random 4B global writes/atomics -> ~10x line-writeback amp.
// R5: CSR build = 2-level bucket sort, zero global random atomics.
// R6/R7/R14 ALL FAILED (L2-locality for the agg gather): slicing in any
// form regresses. Monolithic agg ~59.5us (~153MB L2-miss @ 2.86TB/s =
// L3 random-256B ceiling) is the floor. Do not retry.
// R12 FAILED: per-edge dinv[src] in the agg loop broke pipelining.
// R16: multisplit overlapped with gemm1 (union dispatch); raw fp16 g +
// row-scale after bucket_build; gcnt/gcur single memset.
// R17/R19: bucket_build 8-deep unrolls ~neutral (compiler already
//   pipelined); gscale fusion into bucket_build tail = the measured -8.5us.
//   KEEP fusion. 336.4us baseline.
// R20 (this round): HEAD FUSION. k_gemm_dual_f16 + k_pairs_h replaced by
//   k_pairs_mfma: gather h2[i],h2[j] rows directly as MFMA A-frags
//   (16 pairs/wave), Wh1a/b hi+lo frag tables (128KB) staged in LDS,
//   relu+Wh2 dot in epilogue. Deletes 38MB dual traffic + halves the
//   gather table (25.6->12.8MB) for better L2 hit; one fewer fp16 round.
// R2: fp16 tables (absmax budget ~8e-4 < 1.5e-3 threshold).
// R3: gemm1 (fp32 input) double-bf16-split MFMA (Ah.Bh+Al.Bh+Ah.Bl).
// ---------------------------------------------------------------------------

#define BSH 9                 // log2 nodes per bucket
#define BSZ (1 << BSH)        // 512 nodes per bucket
#define MSB 4096              // edges per multisplit batch/block
#define XPAD 132              // LDS row stride (floats) for fp32 gemm staging
#define HB 256                // hist blocks in fused K1

typedef __attribute__((ext_vector_type(8))) short bf16x8;
typedef __attribute__((ext_vector_type(8))) _Float16 f16x8;
typedef __attribute__((ext_vector_type(4))) float f32x4;
typedef __attribute__((ext_vector_type(4))) int i32x4;

__device__ __forceinline__ void acc8(uint4 u, float4& lo, float4& hi) {
  float2 f0 = __half22float2(((const __half2*)&u)[0]);
  float2 f1 = __half22float2(((const __half2*)&u)[1]);
  float2 f2 = __half22float2(((const __half2*)&u)[2]);
  float2 f3 = __half22float2(((const __half2*)&u)[3]);
  lo.x += f0.x; lo.y += f0.y; lo.z += f1.x; lo.w += f1.y;
  hi.x += f2.x; hi.y += f2.y; hi.z += f3.x; hi.w += f3.y;
}

// Exact fp32 -> bf16 hi/lo split.
__device__ __forceinline__ void split8(const float* v, bf16x8& hi, bf16x8& lo) {
#pragma unroll
  for (int j = 0; j < 8; ++j) {
    unsigned u = __float_as_uint(v[j]);
    hi[j] = (short)(u >> 16);
    float lf = v[j] - __uint_as_float(u & 0xffff0000u);
    lo[j] = (short)(__float_as_uint(lf) >> 16);
  }
}

// K1: weight fragment prep UNION dst bucket-histogram (gc pre-zeroed).
// hist: 4-wide loads (dst is 16B-aligned: offset E*4B, E multiple of 4).
__global__ __launch_bounds__(256) void k_prep_hist(
    const float* __restrict__ W1, const float* __restrict__ W2,
    const float* __restrict__ Wh1, short* __restrict__ fragH,
    short* __restrict__ fragL,
    const int* __restrict__ dst, int* __restrict__ gcnt, int e, int kb) {
  if (blockIdx.x >= 32) {
    __shared__ int h4[512];
    int bid = blockIdx.x - 32;
    int tid = threadIdx.x, wid = tid >> 6;
    for (int t = tid; t < 512; t += 256) h4[t] = 0;
    __syncthreads();
    const i32x4* dst4 = (const i32x4*)dst;
    int ne4 = e >> 2;
    const int STR = HB * 256;
    int i = bid * 256 + tid;
    for (; i < ne4 - STR; i += 2 * STR) {
      i32x4 a = __builtin_nontemporal_load(&dst4[i]);
      i32x4 b = __builtin_nontemporal_load(&dst4[i + STR]);
      atomicAdd(&h4[wid * 128 + (a.x >> BSH)], 1);
      atomicAdd(&h4[wid * 128 + (a.y >> BSH)], 1);
      atomicAdd(&h4[wid * 128 + (a.z >> BSH)], 1);
      atomicAdd(&h4[wid * 128 + (a.w >> BSH)], 1);
      atomicAdd(&h4[wid * 128 + (b.x >> BSH)], 1);
      atomicAdd(&h4[wid * 128 + (b.y >> BSH)], 1);
      atomicAdd(&h4[wid * 128 + (b.z >> BSH)], 1);
      atomicAdd(&h4[wid * 128 + (b.w >> BSH)], 1);
    }
    for (; i < ne4; i += STR) {
      i32x4 a = __builtin_nontemporal_load(&dst4[i]);
      atomicAdd(&h4[wid * 128 + (a.x >> BSH)], 1);
      atomicAdd(&h4[wid * 128 + (a.y >> BSH)], 1);
      atomicAdd(&h4[wid * 128 + (a.z >> BSH)], 1);
      atomicAdd(&h4[wid * 128 + (a.w >> BSH)], 1);
    }
    if (bid == 0 && tid < (e & 3)) {
      int d = dst[(ne4 << 2) + tid];
      atomicAdd(&h4[wid * 128 + (d >> BSH)], 1);
    }
    __syncthreads();
    if (tid < kb)
      atomicAdd(&gcnt[tid], h4[tid] + h4[128 + tid] + h4[256 + tid] + h4[384 + tid]);
    return;
  }
  int g = blockIdx.x * 256 + threadIdx.x;
  int w = g >> 11;
  int rem = g & 2047;
  int lane = rem & 63;
  int ts = rem >> 6;
  int t = ts >> 2, s = ts & 3;
  int n = (t << 4) + (lane & 15);
  int k0 = s * 32 + (lane >> 4) * 8;
  const float* W = (w == 0) ? W1 : (w == 1) ? W2 : (w == 2) ? Wh1 : (Wh1 + 128 * 128);
  short h[8], l[8];
#pragma unroll
  for (int j = 0; j < 8; ++j) {
    float x = W[(k0 + j) * 128 + n];
    if (w == 0) {
      unsigned u = __float_as_uint(x);
      h[j] = (short)(u >> 16);
      float lf = x - __uint_as_float(u & 0xffff0000u);
      l[j] = (short)(__float_as_uint(lf) >> 16);
    } else {
      __half hh = __float2half(x);
      h[j] = __half_as_short(hh);
      l[j] = __half_as_short(__float2half(x - __half2float(hh)));
    }
  }
  ((int4*)fragH)[g] = *(int4*)h;
  ((int4*)fragL)[g] = *(int4*)l;
}

// fp32-input gemm body, NO rowscale (raw fp16 out); sX = 64*XPAD floats LDS.
__device__ __forceinline__ void gemm1_body(
    const float* __restrict__ X, const short* __restrict__ fragH,
    const short* __restrict__ fragL, __half* __restrict__ C16, int n,
    int bid, float* sX) {
  int tid = threadIdx.x;
  int row0 = bid * 64;
  const float2* X2 = (const float2*)(X + (size_t)row0 * 128);
#pragma unroll
  for (int it = 0; it < 16; ++it) {
    int t = it * 256 + tid;
    int r = t >> 6, c2 = t & 63;
    int gr = row0 + r;
    float2 v = (gr < n) ? X2[t] : make_float2(0.f, 0.f);
    *(float2*)&sX[r * XPAD + c2 * 2] = v;
  }
  __syncthreads();
  int wid = tid >> 6, lane = tid & 63;
  int r0 = row0 + wid * 16;
  if (r0 >= n) return;
  int m = lane & 15, quad = lane >> 4;
  const float* xrow = sX + (wid * 16 + m) * XPAD;
  f32x4 acc[8];
#pragma unroll
  for (int t = 0; t < 8; ++t) acc[t] = (f32x4)(0.f);
  const int4* FH = (const int4*)fragH;
  const int4* FL = (const int4*)fragL;
#pragma unroll
  for (int s = 0; s < 4; ++s) {
    int k0 = s * 32 + quad * 8;
    float xv[8];
    *(float2*)&xv[0] = *(const float2*)(xrow + k0);
    *(float2*)&xv[2] = *(const float2*)(xrow + k0 + 2);
    *(float2*)&xv[4] = *(const float2*)(xrow + k0 + 4);
    *(float2*)&xv[6] = *(const float2*)(xrow + k0 + 6);
    bf16x8 ah, al;
    split8(xv, ah, al);
#pragma unroll
    for (int t = 0; t < 8; ++t) {
      int idx = (t * 4 + s) * 64 + lane;
      bf16x8 bh = *(const bf16x8*)&FH[idx];
      bf16x8 bl = *(const bf16x8*)&FL[idx];
      acc[t] = __builtin_amdgcn_mfma_f32_16x16x32_bf16(ah, bh, acc[t], 0, 0, 0);
      acc[t] = __builtin_amdgcn_mfma_f32_16x16x32_bf16(al, bh, acc[t], 0, 0, 0);
      acc[t] = __builtin_amdgcn_mfma_f32_16x16x32_bf16(ah, bl, acc[t], 0, 0, 0);
    }
  }
  // C/D layout: col = lane&15, row = quad*4 + reg   [m89-verified]
#pragma unroll
  for (int t = 0; t < 8; ++t) {
#pragma unroll
    for (int r = 0; r < 4; ++r) {
      int row = r0 + quad * 4 + r;
      C16[(size_t)row * 128 + t * 16 + m] = __float2half(acc[t][r]);
    }
  }
}

// multisplit body: per-wave replicated LDS hist; in-block scan of gcnt; one
// global atomic per bucket per batch. packed = (d_local<<16)|src [src<65536]
// lds = at least 4*128 + 4*128 + 128 + 2 ints.
__device__ __forceinline__ void multisplit_body(
    const int* __restrict__ src, const int* __restrict__ dst,
    const int* __restrict__ gcnt, int* __restrict__ gcur,
    int* __restrict__ tmp, int e, int kb, int bid, int* lds) {
  int* h4 = lds;            // 512
  int* off = lds + 512;     // 512
  int* sbase = lds + 1024;  // 128
  int* ws = lds + 1152;     // 2
  int tid = threadIdx.x, wid = tid >> 6, lane = tid & 63;
  for (int t = tid; t < 512; t += 256) h4[t] = 0;
  __syncthreads();
  int i0 = bid * MSB + tid;
  int d[16], rk[16];
#pragma unroll
  for (int u = 0; u < 16; ++u) {
    int i = i0 + u * 256;
    if (i < e) {
      d[u] = __builtin_nontemporal_load(&dst[i]);
      rk[u] = atomicAdd(&h4[wid * 128 + (d[u] >> BSH)], 1);
    }
  }
  __syncthreads();
  int tot = 0;
  if (tid < 128) {
    int c0 = h4[tid], c1 = h4[128 + tid], c2 = h4[256 + tid], c3 = h4[384 + tid];
    off[tid] = 0; off[128 + tid] = c0;
    off[256 + tid] = c0 + c1; off[384 + tid] = c0 + c1 + c2;
    tot = c0 + c1 + c2 + c3;
  }
  int v = (tid < 128 && tid < kb) ? gcnt[tid] : 0;
  int orig = v;
#pragma unroll
  for (int o = 1; o < 64; o <<= 1) {
    int u = __shfl_up(v, o, 64);
    if (lane >= o) v += u;
  }
  if (lane == 63 && wid < 2) ws[wid] = v;
  __syncthreads();
  if (tid < 128) sbase[tid] = ((wid == 1) ? ws[0] : 0) + v - orig;
  __syncthreads();
  if (tid < kb && tot > 0) sbase[tid] += atomicAdd(&gcur[tid], tot);
  __syncthreads();
#pragma unroll
  for (int u = 0; u < 16; ++u) {
    int i = i0 + u * 256;
    if (i < e) {
      int s = __builtin_nontemporal_load(&src[i]);
      int k = d[u] >> BSH;
      tmp[sbase[k] + off[wid * 128 + k] + rk[u]] = ((d[u] & (BSZ - 1)) << 16) | s;
    }
  }
}

// K2: multisplit UNION gemm1 (both independent: ms needs gcnt/gcur from K1/
// memset; gemm1 needs only W1 frags + x). Overlaps CSR edge pass with GEMM.
__global__ __launch_bounds__(256) void k_ms_gemm1(
    const int* __restrict__ src, const int* __restrict__ dst,
    const int* __restrict__ gcnt, int* __restrict__ gcur,
    int* __restrict__ tmp, int e, int kb, int msblocks,
    const float* __restrict__ X, const short* __restrict__ fragH,
    const short* __restrict__ fragL, __half* __restrict__ C16, int n) {
  __shared__ float sX[64 * XPAD];
  if ((int)blockIdx.x < msblocks) {
    multisplit_body(src, dst, gcnt, gcur, tmp, e, kb, blockIdx.x, (int*)sX);
    return;
  }
  gemm1_body(X, fragH, fragL, C16, n, blockIdx.x - msblocks, sX);
}

// one block per bucket: in-block scan of gcnt; per-node degree + scan +
// cursor scatter in LDS. colarr u16, bucket-local (no write-amp).
// R17: 8-deep unrolled passes; gscale fused into tail (measured -8.5us).
__global__ __launch_bounds__(512) void k_bucket_build(
    const int* __restrict__ tmp, const int* __restrict__ gcnt,
    int* __restrict__ rowptr, float* __restrict__ dinv,
    unsigned short* __restrict__ colarr, __half* __restrict__ g16,
    int n, int kb, int e) {
  __shared__ int dl[BSZ], cl[BSZ], sbase[128], ws[8];
  __shared__ float sdi[BSZ];
  int t = threadIdx.x, b = blockIdx.x;
  int lane = t & 63, w = t >> 6;
  int v = (t < 128 && t < kb) ? gcnt[t] : 0;
  int orig0 = v;
#pragma unroll
  for (int o = 1; o < 64; o <<= 1) {
    int u = __shfl_up(v, o, 64);
    if (lane >= o) v += u;
  }
  if (lane == 63 && w < 2) ws[w] = v;
  dl[t] = 0;
  __syncthreads();
  if (t < 128) sbase[t] = ((w == 1) ? ws[0] : 0) + v - orig0;
  __syncthreads();
  int s0 = sbase[b];
  int s1 = s0 + gcnt[b];
  // pass 1: per-node degree histogram, 8 loads in flight
  {
    int j = s0 + t;
    for (; j < s1 - 3584; j += 4096) {
      int v0 = tmp[j];
      int v1 = tmp[j + 512];
      int v2 = tmp[j + 1024];
      int v3 = tmp[j + 1536];
      int v4 = tmp[j + 2048];
      int v5 = tmp[j + 2560];
      int v6 = tmp[j + 3072];
      int v7 = tmp[j + 3584];
      atomicAdd(&dl[((unsigned)v0) >> 16], 1);
      atomicAdd(&dl[((unsigned)v1) >> 16], 1);
      atomicAdd(&dl[((unsigned)v2) >> 16], 1);
      atomicAdd(&dl[((unsigned)v3) >> 16], 1);
      atomicAdd(&dl[((unsigned)v4) >> 16], 1);
      atomicAdd(&dl[((unsigned)v5) >> 16], 1);
      atomicAdd(&dl[((unsigned)v6) >> 16], 1);
      atomicAdd(&dl[((unsigned)v7) >> 16], 1);
    }
    for (; j < s1; j += 512)
      atomicAdd(&dl[((unsigned)tmp[j]) >> 16], 1);
  }
  __syncthreads();
  int dv = dl[t], orig = dv;
#pragma unroll
  for (int o = 1; o < 64; o <<= 1) {
    int u = __shfl_up(dv, o, 64);
    if (lane >= o) dv += u;
  }
  if (lane == 63) ws[w] = dv;
  __syncthreads();
  if (t == 0) {
    int a = 0;
#pragma unroll
    for (int k = 0; k < 8; ++k) { int x = ws[k]; ws[k] = a; a += x; }
  }
  __syncthreads();
  int ex = ws[w] + dv - orig;
  cl[t] = ex;
  int node = (b << BSH) + t;
  float di = rsqrtf((float)(orig + 1));  // +1 self loop
  sdi[t] = di;
  if (node < n) {
    rowptr[node] = s0 + ex;
    dinv[node] = di;
  }
  if (b == kb - 1 && t == 0) rowptr[n] = e;
  __syncthreads();
  // pass 2: cursor scatter, 8 loads in flight
  {
    int j = s0 + t;
    for (; j < s1 - 3584; j += 4096) {
      int p0 = tmp[j];
      int p1 = tmp[j + 512];
      int p2 = tmp[j + 1024];
      int p3 = tmp[j + 1536];
      int p4 = tmp[j + 2048];
      int p5 = tmp[j + 2560];
      int p6 = tmp[j + 3072];
      int p7 = tmp[j + 3584];
      int r0 = atomicAdd(&cl[((unsigned)p0) >> 16], 1);
      int r1 = atomicAdd(&cl[((unsigned)p1) >> 16], 1);
      int r2 = atomicAdd(&cl[((unsigned)p2) >> 16], 1);
      int r3 = atomicAdd(&cl[((unsigned)p3) >> 16], 1);
      int r4 = atomicAdd(&cl[((unsigned)p4) >> 16], 1);
      int r5 = atomicAdd(&cl[((unsigned)p5) >> 16], 1);
      int r6 = atomicAdd(&cl[((unsigned)p6) >> 16], 1);
      int r7 = atomicAdd(&cl[((unsigned)p7) >> 16], 1);
      colarr[s0 + r0] = (unsigned short)(p0 & 0xFFFF);
      colarr[s0 + r1] = (unsigned short)(p1 & 0xFFFF);
      colarr[s0 + r2] = (unsigned short)(p2 & 0xFFFF);
      colarr[s0 + r3] = (unsigned short)(p3 & 0xFFFF);
      colarr[s0 + r4] = (unsigned short)(p4 & 0xFFFF);
      colarr[s0 + r5] = (unsigned short)(p5 & 0xFFFF);
      colarr[s0 + r6] = (unsigned short)(p6 & 0xFFFF);
      colarr[s0 + r7] = (unsigned short)(p7 & 0xFFFF);
    }
    for (; j < s1; j += 512) {
      int p = tmp[j];
      int r = atomicAdd(&cl[((unsigned)p) >> 16], 1);
      colarr[s0 + r] = (unsigned short)(p & 0xFFFF);
    }
  }
  // fused gscale (was K4): scale this bucket's rows of g16 by dinv.
  // coalesced: 16 consecutive lanes = one 256B row.
  {
    int base = b << BSH;
    int rows = n - base;
    if (rows > BSZ) rows = BSZ;
    uint4* G = (uint4*)g16;
    for (int idx = t; idx < rows * 16; idx += 512) {
      int rl = idx >> 4;
      float dsc = sdi[rl];
      size_t gi = (size_t)(base + rl) * 16 + (idx & 15);
      uint4 u = G[gi];
      __half2* hp = (__half2*)&u;
#pragma unroll
      for (int k2 = 0; k2 < 4; ++k2) {
        float2 f = __half22float2(hp[k2]);
        hp[k2] = __floats2half2_rn(f.x * dsc, f.y * dsc);
      }
      G[gi] = u;
    }
  }
}

// f16-input GEMM: C16 = fp16(rowscale * X16 @ W), A fp16-exact, B f16 hi+lo.
__global__ __launch_bounds__(256) void k_gemm_f16(
    const __half* __restrict__ X16, const short* __restrict__ fragH,
    const short* __restrict__ fragL, const float* __restrict__ rowscale,
    __half* __restrict__ C16, int n) {
  int wid = threadIdx.x >> 6, lane = threadIdx.x & 63;
  int r0 = (blockIdx.x * 4 + wid) * 16;
  if (r0 >= n) return;
  int m = lane & 15, quad = lane >> 4;
  const uint4* Xr = (const uint4*)(X16 + (size_t)(r0 + m) * 128);
  f32x4 acc[8];
#pragma unroll
  for (int t = 0; t < 8; ++t) acc[t] = (f32x4)(0.f);
  const int4* FH = (const int4*)fragH;
  const int4* FL = (const int4*)fragL;
#pragma unroll
  for (int s = 0; s < 4; ++s) {
    uint4 av = Xr[quad + 4 * s];
    f16x8 a = *(const f16x8*)&av;
#pragma unroll
    for (int t = 0; t < 8; ++t) {
      int idx = (t * 4 + s) * 64 + lane;
      int4 bhv = FH[idx], blv = FL[idx];
      f16x8 bh = *(const f16x8*)&bhv;
      f16x8 bl = *(const f16x8*)&blv;
      acc[t] = __builtin_amdgcn_mfma_f32_16x16x32_f16(a, bh, acc[t], 0, 0, 0);
      acc[t] = __builtin_amdgcn_mfma_f32_16x16x32_f16(a, bl, acc[t], 0, 0, 0);
    }
  }
  float sc[4];
#pragma unroll
  for (int r = 0; r < 4; ++r)
    sc[r] = rowscale ? rowscale[r0 + quad * 4 + r] : 1.f;
#pragma unroll
  for (int t = 0; t < 8; ++t) {
#pragma unroll
    for (int r = 0; r < 4; ++r) {
      int row = r0 + quad * 4 + r;
      C16[(size_t)row * 128 + t * 16 + m] = __float2half(acc[t][r] * sc[r]);
    }
  }
}

// out16[i,:] = fp16(relu(dinv[i] * (g[i,:] + sum g[col[e],:]) + bias))
// R13 known-good monolithic gather: uint4 lanes, 4 edge subgroups, 4-deep
// unroll = 16 edges in flight. DO NOT slice (R6/R7/R14 all regressed).
__global__ __launch_bounds__(256) void k_agg_h(
    const __half2* __restrict__ g2, const float* __restrict__ dinv,
    const int* __restrict__ rowptr, const unsigned short* __restrict__ col,
    const float* __restrict__ bias, __half* __restrict__ out16, int n) {
  int i = blockIdx.x * 4 + (threadIdx.x >> 6);
  if (i >= n) return;
  int lane = threadIdx.x & 63;
  int sub = lane >> 4;
  int c8 = lane & 15;
  const uint4* G = (const uint4*)g2;
  float4 z = make_float4(0.f, 0.f, 0.f, 0.f);
  float4 lo0 = z, lo1 = z, lo2 = z, lo3 = z, hi0 = z, hi1 = z, hi2 = z, hi3 = z;
  if (sub == 0) acc8(G[(size_t)i * 16 + c8], lo0, hi0);  // self loop once
  int beg = rowptr[i], end = rowptr[i + 1];
  int j = beg;
  for (; j + 16 <= end; j += 16) {
    int s0 = __builtin_nontemporal_load(&col[j + sub]);
    int s1 = __builtin_nontemporal_load(&col[j + 4 + sub]);
    int s2 = __builtin_nontemporal_load(&col[j + 8 + sub]);
    int s3 = __builtin_nontemporal_load(&col[j + 12 + sub]);
    uint4 u0 = G[(size_t)s0 * 16 + c8];
    uint4 u1 = G[(size_t)s1 * 16 + c8];
    uint4 u2 = G[(size_t)s2 * 16 + c8];
    uint4 u3 = G[(size_t)s3 * 16 + c8];
    acc8(u0, lo0, hi0); acc8(u1, lo1, hi1);
    acc8(u2, lo2, hi2); acc8(u3, lo3, hi3);
  }
  for (; j + 4 <= end; j += 4) {
    int s0 = __builtin_nontemporal_load(&col[j + sub]);
    acc8(G[(size_t)s0 * 16 + c8], lo1, hi1);
  }
  int rem = end - j;
  if (sub < rem) {
    int s0 = __builtin_nontemporal_load(&col[j + sub]);
    acc8(G[(size_t)s0 * 16 + c8], lo2, hi2);
  }
  float4 lo, hi;
  lo.x = (lo0.x + lo1.x) + (lo2.x + lo3.x);
  lo.y = (lo0.y + lo1.y) + (lo2.y + lo3.y);
  lo.z = (lo0.z + lo1.z) + (lo2.z + lo3.z);
  lo.w = (lo0.w + lo1.w) + (lo2.w + lo3.w);
  hi.x = (hi0.x + hi1.x) + (hi2.x + hi3.x);
  hi.y = (hi0.y + hi1.y) + (hi2.y + hi3.y);
  hi.z = (hi0.z + hi1.z) + (hi2.z + hi3.z);
  hi.w = (hi0.w + hi1.w) + (hi2.w + hi3.w);
  lo.x += __shfl_down(lo.x, 32, 64); lo.x += __shfl_down(lo.x, 16, 64);
  lo.y += __shfl_down(lo.y, 32, 64); lo.y += __shfl_down(lo.y, 16, 64);
  lo.z += __shfl_down(lo.z, 32, 64); lo.z += __shfl_down(lo.z, 16, 64);
  lo.w += __shfl_down(lo.w, 32, 64); lo.w += __shfl_down(lo.w, 16, 64);
  hi.x += __shfl_down(hi.x, 32, 64); hi.x += __shfl_down(hi.x, 16, 64);
  hi.y += __shfl_down(hi.y, 32, 64); hi.y += __shfl_down(hi.y, 16, 64);
  hi.z += __shfl_down(hi.z, 32, 64); hi.z += __shfl_down(hi.z, 16, 64);
  hi.w += __shfl_down(hi.w, 32, 64); hi.w += __shfl_down(hi.w, 16, 64);
  if (sub == 0) {
    float di = dinv[i];
    float4 b0 = ((const float4*)bias)[2 * c8];
    float4 b1 = ((const float4*)bias)[2 * c8 + 1];
    __half2 q0 = __floats2half2_rn(fmaxf(fmaf(di, lo.x, b0.x), 0.f),
                                   fmaxf(fmaf(di, lo.y, b0.y), 0.f));
    __half2 q1 = __floats2half2_rn(fmaxf(fmaf(di, lo.z, b0.z), 0.f),
                                   fmaxf(fmaf(di, lo.w, b0.w), 0.f));
    __half2 q2 = __floats2half2_rn(fmaxf(fmaf(di, hi.x, b1.x), 0.f),
                                   fmaxf(fmaf(di, hi.y, b1.y), 0.f));
    __half2 q3 = __floats2half2_rn(fmaxf(fmaf(di, hi.z, b1.z), 0.f),
                                   fmaxf(fmaf(di, hi.w, b1.w), 0.f));
    uint4 o;
    o.x = *(unsigned*)&q0; o.y = *(unsigned*)&q1;
    o.z = *(unsigned*)&q2; o.w = *(unsigned*)&q3;
    ((uint4*)out16)[(size_t)i * 16 + c8] = o;
  }
}

// R20: fused head. 16 pairs per wave; h2[i],h2[j] gathered directly as MFMA
// A-frags (lane m = pair p0+m, quad q = k-chunk q*8); Wh1a/b hi+lo frag
// tables staged in LDS (128KB, 1 block/CU, 16 waves = 4/SIMD).
// hidden = relu(h2i@Wh1a + h2j@Wh1b + bh1); out = hidden . Wh2 + bh2.
// C layout col=lane&15, row=quad*4+reg [m89] -> lane (q,m) holds pairs
// q*4+r at cols t*16+m; dot Wh2 per lane, shfl-reduce over 16 m-lanes.
__global__ __launch_bounds__(1024) void k_pairs_mfma(
    const __half* __restrict__ h2,
    const short* __restrict__ fHa, const short* __restrict__ fLa,
    const short* __restrict__ fHb, const short* __restrict__ fLb,
    const int* __restrict__ pairs, const float* __restrict__ bh1,
    const float* __restrict__ wh2, const float* __restrict__ bh2,
    float* __restrict__ out, int P) {
  __shared__ int4 sF[4][2048];  // Ha, La, Hb, Lb = 128KB
  {
    const int4* g0 = (const int4*)fHa;
    const int4* g1 = (const int4*)fLa;
    const int4* g2 = (const int4*)fHb;
    const int4* g3 = (const int4*)fLb;
    for (int t = threadIdx.x; t < 2048; t += 1024) {
      sF[0][t] = g0[t];
      sF[1][t] = g1[t];
      sF[2][t] = g2[t];
      sF[3][t] = g3[t];
    }
  }
  __syncthreads();
  int w = threadIdx.x >> 6, lane = threadIdx.x & 63;
  int m = lane & 15, quad = lane >> 4;
  int p0 = blockIdx.x * 256 + w * 16;
  int pm = p0 + m;
  int iA = 0, jB = 0;
  if (pm < P) {
    iA = pairs[2 * pm];
    jB = pairs[2 * pm + 1];
  }
  const __half* ri = h2 + (size_t)iA * 128 + quad * 8;
  const __half* rj = h2 + (size_t)jB * 128 + quad * 8;
  f16x8 ai[4], aj[4];
#pragma unroll
  for (int s = 0; s < 4; ++s) {
    ai[s] = *(const f16x8*)(ri + s * 32);
    aj[s] = *(const f16x8*)(rj + s * 32);
  }
  f32x4 acc[8];
#pragma unroll
  for (int t = 0; t < 8; ++t) acc[t] = (f32x4)(0.f);
#pragma unroll
  for (int s = 0; s < 4; ++s) {
#pragma unroll
    for (int t = 0; t < 8; ++t) {
      int idx = (t * 4 + s) * 64 + lane;
      int4 vha = sF[0][idx], vla = sF[1][idx];
      int4 vhb = sF[2][idx], vlb = sF[3][idx];
      acc[t] = __builtin_amdgcn_mfma_f32_16x16x32_f16(ai[s], *(const f16x8*)&vha, acc[t], 0, 0, 0);
      acc[t] = __builtin_amdgcn_mfma_f32_16x16x32_f16(ai[s], *(const f16x8*)&vla, acc[t], 0, 0, 0);
      acc[t] = __builtin_amdgcn_mfma_f32_16x16x32_f16(aj[s], *(const f16x8*)&vhb, acc[t], 0, 0, 0);
      acc[t] = __builtin_amdgcn_mfma_f32_16x16x32_f16(aj[s], *(const f16x8*)&vlb, acc[t], 0, 0, 0);
    }
  }
  float sP[4] = {0.f, 0.f, 0.f, 0.f};
#pragma unroll
  for (int t = 0; t < 8; ++t) {
    float bb = bh1[t * 16 + m];
    float ww = wh2[t * 16 + m];
#pragma unroll
    for (int r = 0; r < 4; ++r)
      sP[r] += fmaxf(acc[t][r] + bb, 0.f) * ww;
  }
#pragma unroll
  for (int o = 8; o > 0; o >>= 1) {
#pragma unroll
    for (int r = 0; r < 4; ++r) sP[r] += __shfl_down(sP[r], o, 64);
  }
  if (m == 0) {
    float bb2 = bh2[0];
#pragma unroll
    for (int r = 0; r < 4; ++r) {
      int p = p0 + quad * 4 + r;
      if (p < P) out[p] = sP[r] + bb2;
    }
  }
}

extern "C" void kernel_launch(void* const* d_in, const int* in_sizes, int n_in,
                              void* d_out, int out_size, void* d_ws, size_t ws_size,
                              hipStream_t stream) {
  const float* x   = (const float*)d_in[0];
  const int* ei    = (const int*)d_in[1];
  const int* pairs = (const int*)d_in[2];
  const float* W1  = (const float*)d_in[3];
  const float* b1  = (const float*)d_in[4];
  const float* W2  = (const float*)d_in[5];
  const float* b2  = (const float*)d_in[6];
  const float* Wh1 = (const float*)d_in[7];
  const float* bh1 = (const float*)d_in[8];
  const float* Wh2 = (const float*)d_in[9];
  const float* bh2 = (const float*)d_in[10];
  (void)n_in; (void)out_size; (void)ws_size;

  int N = in_sizes[0] / 128;
  int E = in_sizes[1] / 2;
  int P = in_sizes[2] / 2;
  const int* src = ei;
  const int* dst = ei + E;
  int KB = (N + BSZ - 1) >> BSH;  // buckets (98 for N=50000)

  char* wsp = (char*)d_ws;
  size_t off = 0;
  auto alloc = [&](size_t bytes) -> void* {
    void* p = wsp + off;
    off += (bytes + 255) & ~(size_t)255;
    return p;
  };
  __half* g16 = (__half*)alloc((size_t)N * 128 * 2);  // messages
  __half* h1  = (__half*)alloc((size_t)N * 128 * 2);  // fp16
  __half* h2  = (__half*)alloc((size_t)N * 128 * 2);  // fp16
  float* dinv = (float*)alloc((size_t)N * 4);
  int* rowptr = (int*)alloc((size_t)(N + 1) * 4);
  unsigned short* colarr = (unsigned short*)alloc((size_t)E * 2);
  int* tmp    = (int*)alloc((size_t)E * 4);
  short* fragH = (short*)alloc(4 * 2048 * 8 * 2);     // 128KB
  short* fragL = (short*)alloc(4 * 2048 * 8 * 2);     // 128KB
  int* gc     = (int*)alloc(2 * 128 * 4);             // [0:128) gcnt, [128:256) gcur
  int* gcnt = gc;
  int* gcur = gc + 128;
  short* fH_W1 = fragH + 0 * 16384;  short* fL_W1 = fragL + 0 * 16384;
  short* fH_W2 = fragH + 1 * 16384;  short* fL_W2 = fragL + 1 * 16384;
  short* fH_Wa = fragH + 2 * 16384;  short* fL_Wa = fragL + 2 * 16384;
  short* fH_Wb = fragH + 3 * 16384;  short* fL_Wb = fragL + 3 * 16384;

  int GB = (N + 63) / 64;          // fp32 gemm: 64 rows per block
  int GF = (N / 16 + 3) / 4;       // f16 gemm: 16 rows/wave, 4 waves/block
  int AB = (N + 3) / 4;            // agg: 4 rows per block
  int MS = (E + MSB - 1) / MSB;    // multisplit blocks

  // one memset for both counter arrays, then fused prep+hist
  hipMemsetAsync(gc, 0, 2 * 128 * 4, stream);
  k_prep_hist<<<32 + HB, 256, 0, stream>>>(W1, W2, Wh1, fragH, fragL,
                                           dst, gcnt, E, KB);
  // K2: multisplit UNION gemm1 (raw, unscaled)
  k_ms_gemm1<<<MS + GB, 256, 0, stream>>>(src, dst, gcnt, gcur, tmp, E, KB, MS,
                                          x, fH_W1, fL_W1, g16, N);
  // K3: per-bucket LDS sort -> rowptr/dinv/colarr, then fused g16 row-scale
  k_bucket_build<<<KB, 512, 0, stream>>>(tmp, gcnt, rowptr, dinv, colarr,
                                         g16, N, KB, E);
  // conv1 agg
  k_agg_h<<<AB, 256, 0, stream>>>((const __half2*)g16, dinv, rowptr, colarr, b1, h1, N);
  // conv2 (f16 path)
  k_gemm_f16<<<GF, 256, 0, stream>>>(h1, fH_W2, fL_W2, dinv, g16, N);
  k_agg_h<<<AB, 256, 0, stream>>>((const __half2*)g16, dinv, rowptr, colarr, b2, h2, N);
  // head: fused dual-gemm + pairs (R20)
  k_pairs_mfma<<<(P + 255) / 256, 1024, 0, stream>>>(
      h2, fH_Wa, fL_Wa, fH_Wb, fL_Wb, pairs, bh1, Wh2, bh2,
      (float*)d_out, P);
}

// Round 6
// 331.256 us; speedup vs baseline: 1.0413x; 1.0057x over previous
//
#include <hip/hip_runtime.h>
#include <hip/hip_fp16.h>

// ---------------------------------------------------------------------------
// LinkPredictionGNN: 2x GCNConv (self-loops, sym-norm) + pair MLP head.
//   memset gc -> K1 prep_w UNION hist -> K2 multisplit UNION gemm1(raw)
//   -> K3 bucket_build (+fused gscale) -> K5 agg1 -> K6 gemm2_f16
//   -> K7 agg2 -> K8 pairs_mfma (fused dual-gemm + pair head)
//
// R1/R4: random 4B global writes/atomics -> ~10x line-writeback amp.
// R5: CSR build = 2-level bucket sort, zero global random atomics.
// R6/R7/R14 ALL FAILED (L2-locality for the agg gather): slicing in any
// form regresses. Monolithic agg ~59.5us (~153MB L2-miss @ 2.86TB/s =
// L3 random-256B ceiling) is the floor. Do not retry.
// R12 FAILED: per-edge dinv[src] in the agg loop broke pipelining.
// R16: multisplit overlapped with gemm1 (union dispatch); raw fp16 g +
// row-scale after bucket_build; gcnt/gcur single memset.
// R17/R19: bucket_build 8-deep unrolls ~neutral; gscale fusion into
//   bucket_build tail = measured -8.5us. KEEP fusion.
// R20: head fusion (dual+pairs -> pairs_mfma): -3.3us only; old head was
//   L2-resident/cheap. 333.2us baseline. Keep (less traffic, one launch).
// R21: gemm1 de-LDS. A-tile has ZERO reuse (each x row feeds one wave)
//   and B comes from L2 frag tables -> LDS staging was pure overhead.
//   Direct per-lane float4 loads; union kernel LDS 33.8KB -> 4.6KB =>
//   occupancy up for both halves; staging loop + barrier deleted.
//   Bit-identical numerics.
// R22 (this round): resubmit of R21 - GPU broker timeout, no data.
// R2: fp16 tables (absmax budget ~8e-4 < 1.5e-3 threshold).
// R3: gemm1 (fp32 input) double-bf16-split MFMA (Ah.Bh+Al.Bh+Ah.Bl).
// ---------------------------------------------------------------------------

#define BSH 9                 // log2 nodes per bucket
#define BSZ (1 << BSH)        // 512 nodes per bucket
#define MSB 4096              // edges per multisplit batch/block
#define HB 256                // hist blocks in fused K1
#define MSLDS 1154            // multisplit LDS ints: 512+512+128+2

typedef __attribute__((ext_vector_type(8))) short bf16x8;
typedef __attribute__((ext_vector_type(8))) _Float16 f16x8;
typedef __attribute__((ext_vector_type(4))) float f32x4;
typedef __attribute__((ext_vector_type(4))) int i32x4;

__device__ __forceinline__ void acc8(uint4 u, float4& lo, float4& hi) {
  float2 f0 = __half22float2(((const __half2*)&u)[0]);
  float2 f1 = __half22float2(((const __half2*)&u)[1]);
  float2 f2 = __half22float2(((const __half2*)&u)[2]);
  float2 f3 = __half22float2(((const __half2*)&u)[3]);
  lo.x += f0.x; lo.y += f0.y; lo.z += f1.x; lo.w += f1.y;
  hi.x += f2.x; hi.y += f2.y; hi.z += f3.x; hi.w += f3.y;
}

// Exact fp32 -> bf16 hi/lo split.
__device__ __forceinline__ void split8(const float* v, bf16x8& hi, bf16x8& lo) {
#pragma unroll
  for (int j = 0; j < 8; ++j) {
    unsigned u = __float_as_uint(v[j]);
    hi[j] = (short)(u >> 16);
    float lf = v[j] - __uint_as_float(u & 0xffff0000u);
    lo[j] = (short)(__float_as_uint(lf) >> 16);
  }
}

// K1: weight fragment prep UNION dst bucket-histogram (gc pre-zeroed).
// hist: 4-wide loads (dst is 16B-aligned: offset E*4B, E multiple of 4).
__global__ __launch_bounds__(256) void k_prep_hist(
    const float* __restrict__ W1, const float* __restrict__ W2,
    const float* __restrict__ Wh1, short* __restrict__ fragH,
    short* __restrict__ fragL,
    const int* __restrict__ dst, int* __restrict__ gcnt, int e, int kb) {
  if (blockIdx.x >= 32) {
    __shared__ int h4[512];
    int bid = blockIdx.x - 32;
    int tid = threadIdx.x, wid = tid >> 6;
    for (int t = tid; t < 512; t += 256) h4[t] = 0;
    __syncthreads();
    const i32x4* dst4 = (const i32x4*)dst;
    int ne4 = e >> 2;
    const int STR = HB * 256;
    int i = bid * 256 + tid;
    for (; i < ne4 - STR; i += 2 * STR) {
      i32x4 a = __builtin_nontemporal_load(&dst4[i]);
      i32x4 b = __builtin_nontemporal_load(&dst4[i + STR]);
      atomicAdd(&h4[wid * 128 + (a.x >> BSH)], 1);
      atomicAdd(&h4[wid * 128 + (a.y >> BSH)], 1);
      atomicAdd(&h4[wid * 128 + (a.z >> BSH)], 1);
      atomicAdd(&h4[wid * 128 + (a.w >> BSH)], 1);
      atomicAdd(&h4[wid * 128 + (b.x >> BSH)], 1);
      atomicAdd(&h4[wid * 128 + (b.y >> BSH)], 1);
      atomicAdd(&h4[wid * 128 + (b.z >> BSH)], 1);
      atomicAdd(&h4[wid * 128 + (b.w >> BSH)], 1);
    }
    for (; i < ne4; i += STR) {
      i32x4 a = __builtin_nontemporal_load(&dst4[i]);
      atomicAdd(&h4[wid * 128 + (a.x >> BSH)], 1);
      atomicAdd(&h4[wid * 128 + (a.y >> BSH)], 1);
      atomicAdd(&h4[wid * 128 + (a.z >> BSH)], 1);
      atomicAdd(&h4[wid * 128 + (a.w >> BSH)], 1);
    }
    if (bid == 0 && tid < (e & 3)) {
      int d = dst[(ne4 << 2) + tid];
      atomicAdd(&h4[wid * 128 + (d >> BSH)], 1);
    }
    __syncthreads();
    if (tid < kb)
      atomicAdd(&gcnt[tid], h4[tid] + h4[128 + tid] + h4[256 + tid] + h4[384 + tid]);
    return;
  }
  int g = blockIdx.x * 256 + threadIdx.x;
  int w = g >> 11;
  int rem = g & 2047;
  int lane = rem & 63;
  int ts = rem >> 6;
  int t = ts >> 2, s = ts & 3;
  int n = (t << 4) + (lane & 15);
  int k0 = s * 32 + (lane >> 4) * 8;
  const float* W = (w == 0) ? W1 : (w == 1) ? W2 : (w == 2) ? Wh1 : (Wh1 + 128 * 128);
  short h[8], l[8];
#pragma unroll
  for (int j = 0; j < 8; ++j) {
    float x = W[(k0 + j) * 128 + n];
    if (w == 0) {
      unsigned u = __float_as_uint(x);
      h[j] = (short)(u >> 16);
      float lf = x - __uint_as_float(u & 0xffff0000u);
      l[j] = (short)(__float_as_uint(lf) >> 16);
    } else {
      __half hh = __float2half(x);
      h[j] = __half_as_short(hh);
      l[j] = __half_as_short(__float2half(x - __half2float(hh)));
    }
  }
  ((int4*)fragH)[g] = *(int4*)h;
  ((int4*)fragL)[g] = *(int4*)l;
}

// fp32-input gemm body, NO rowscale (raw fp16 out). R21: direct global
// reads (no LDS staging) - A-tile has zero reuse; per s-step a wave reads
// 16 rows x 128B contiguous = 16 full lines. Bit-identical results.
__device__ __forceinline__ void gemm1_body(
    const float* __restrict__ X, const short* __restrict__ fragH,
    const short* __restrict__ fragL, __half* __restrict__ C16, int n,
    int bid) {
  int tid = threadIdx.x;
  int wid = tid >> 6, lane = tid & 63;
  int r0 = bid * 64 + wid * 16;
  if (r0 >= n) return;
  int m = lane & 15, quad = lane >> 4;
  int row = r0 + m;
  if (row > n - 1) row = n - 1;  // safe clamp (n%16==0 in practice)
  const float* xrow = X + (size_t)row * 128 + quad * 8;
  float xv[4][8];
#pragma unroll
  for (int s = 0; s < 4; ++s) {
    *(float4*)&xv[s][0] = *(const float4*)(xrow + s * 32);
    *(float4*)&xv[s][4] = *(const float4*)(xrow + s * 32 + 4);
  }
  f32x4 acc[8];
#pragma unroll
  for (int t = 0; t < 8; ++t) acc[t] = (f32x4)(0.f);
  const int4* FH = (const int4*)fragH;
  const int4* FL = (const int4*)fragL;
#pragma unroll
  for (int s = 0; s < 4; ++s) {
    bf16x8 ah, al;
    split8(xv[s], ah, al);
#pragma unroll
    for (int t = 0; t < 8; ++t) {
      int idx = (t * 4 + s) * 64 + lane;
      bf16x8 bh = *(const bf16x8*)&FH[idx];
      bf16x8 bl = *(const bf16x8*)&FL[idx];
      acc[t] = __builtin_amdgcn_mfma_f32_16x16x32_bf16(ah, bh, acc[t], 0, 0, 0);
      acc[t] = __builtin_amdgcn_mfma_f32_16x16x32_bf16(al, bh, acc[t], 0, 0, 0);
      acc[t] = __builtin_amdgcn_mfma_f32_16x16x32_bf16(ah, bl, acc[t], 0, 0, 0);
    }
  }
  // C/D layout: col = lane&15, row = quad*4 + reg   [m89-verified]
#pragma unroll
  for (int t = 0; t < 8; ++t) {
#pragma unroll
    for (int r = 0; r < 4; ++r) {
      int orow = r0 + quad * 4 + r;
      C16[(size_t)orow * 128 + t * 16 + m] = __float2half(acc[t][r]);
    }
  }
}

// multisplit body: per-wave replicated LDS hist; in-block scan of gcnt; one
// global atomic per bucket per batch. packed = (d_local<<16)|src [src<65536]
__device__ __forceinline__ void multisplit_body(
    const int* __restrict__ src, const int* __restrict__ dst,
    const int* __restrict__ gcnt, int* __restrict__ gcur,
    int* __restrict__ tmp, int e, int kb, int bid, int* lds) {
  int* h4 = lds;            // 512
  int* off = lds + 512;     // 512
  int* sbase = lds + 1024;  // 128
  int* ws = lds + 1152;     // 2
  int tid = threadIdx.x, wid = tid >> 6, lane = tid & 63;
  for (int t = tid; t < 512; t += 256) h4[t] = 0;
  __syncthreads();
  int i0 = bid * MSB + tid;
  int d[16], rk[16];
#pragma unroll
  for (int u = 0; u < 16; ++u) {
    int i = i0 + u * 256;
    if (i < e) {
      d[u] = __builtin_nontemporal_load(&dst[i]);
      rk[u] = atomicAdd(&h4[wid * 128 + (d[u] >> BSH)], 1);
    }
  }
  __syncthreads();
  int tot = 0;
  if (tid < 128) {
    int c0 = h4[tid], c1 = h4[128 + tid], c2 = h4[256 + tid], c3 = h4[384 + tid];
    off[tid] = 0; off[128 + tid] = c0;
    off[256 + tid] = c0 + c1; off[384 + tid] = c0 + c1 + c2;
    tot = c0 + c1 + c2 + c3;
  }
  int v = (tid < 128 && tid < kb) ? gcnt[tid] : 0;
  int orig = v;
#pragma unroll
  for (int o = 1; o < 64; o <<= 1) {
    int u = __shfl_up(v, o, 64);
    if (lane >= o) v += u;
  }
  if (lane == 63 && wid < 2) ws[wid] = v;
  __syncthreads();
  if (tid < 128) sbase[tid] = ((wid == 1) ? ws[0] : 0) + v - orig;
  __syncthreads();
  if (tid < kb && tot > 0) sbase[tid] += atomicAdd(&gcur[tid], tot);
  __syncthreads();
#pragma unroll
  for (int u = 0; u < 16; ++u) {
    int i = i0 + u * 256;
    if (i < e) {
      int s = __builtin_nontemporal_load(&src[i]);
      int k = d[u] >> BSH;
      tmp[sbase[k] + off[wid * 128 + k] + rk[u]] = ((d[u] & (BSZ - 1)) << 16) | s;
    }
  }
}

// K2: multisplit UNION gemm1 (both independent: ms needs gcnt/gcur from K1/
// memset; gemm1 needs only W1 frags + x). R21: LDS = multisplit's 4.6KB
// only (gemm1 reads direct) -> higher occupancy for both halves.
__global__ __launch_bounds__(256) void k_ms_gemm1(
    const int* __restrict__ src, const int* __restrict__ dst,
    const int* __restrict__ gcnt, int* __restrict__ gcur,
    int* __restrict__ tmp, int e, int kb, int msblocks,
    const float* __restrict__ X, const short* __restrict__ fragH,
    const short* __restrict__ fragL, __half* __restrict__ C16, int n) {
  __shared__ int lds[MSLDS];
  if ((int)blockIdx.x < msblocks) {
    multisplit_body(src, dst, gcnt, gcur, tmp, e, kb, blockIdx.x, lds);
    return;
  }
  gemm1_body(X, fragH, fragL, C16, n, blockIdx.x - msblocks);
}

// one block per bucket: in-block scan of gcnt; per-node degree + scan +
// cursor scatter in LDS. colarr u16, bucket-local (no write-amp).
// R17: 8-deep unrolled passes; gscale fused into tail (measured -8.5us).
__global__ __launch_bounds__(512) void k_bucket_build(
    const int* __restrict__ tmp, const int* __restrict__ gcnt,
    int* __restrict__ rowptr, float* __restrict__ dinv,
    unsigned short* __restrict__ colarr, __half* __restrict__ g16,
    int n, int kb, int e) {
  __shared__ int dl[BSZ], cl[BSZ], sbase[128], ws[8];
  __shared__ float sdi[BSZ];
  int t = threadIdx.x, b = blockIdx.x;
  int lane = t & 63, w = t >> 6;
  int v = (t < 128 && t < kb) ? gcnt[t] : 0;
  int orig0 = v;
#pragma unroll
  for (int o = 1; o < 64; o <<= 1) {
    int u = __shfl_up(v, o, 64);
    if (lane >= o) v += u;
  }
  if (lane == 63 && w < 2) ws[w] = v;
  dl[t] = 0;
  __syncthreads();
  if (t < 128) sbase[t] = ((w == 1) ? ws[0] : 0) + v - orig0;
  __syncthreads();
  int s0 = sbase[b];
  int s1 = s0 + gcnt[b];
  // pass 1: per-node degree histogram, 8 loads in flight
  {
    int j = s0 + t;
    for (; j < s1 - 3584; j += 4096) {
      int v0 = tmp[j];
      int v1 = tmp[j + 512];
      int v2 = tmp[j + 1024];
      int v3 = tmp[j + 1536];
      int v4 = tmp[j + 2048];
      int v5 = tmp[j + 2560];
      int v6 = tmp[j + 3072];
      int v7 = tmp[j + 3584];
      atomicAdd(&dl[((unsigned)v0) >> 16], 1);
      atomicAdd(&dl[((unsigned)v1) >> 16], 1);
      atomicAdd(&dl[((unsigned)v2) >> 16], 1);
      atomicAdd(&dl[((unsigned)v3) >> 16], 1);
      atomicAdd(&dl[((unsigned)v4) >> 16], 1);
      atomicAdd(&dl[((unsigned)v5) >> 16], 1);
      atomicAdd(&dl[((unsigned)v6) >> 16], 1);
      atomicAdd(&dl[((unsigned)v7) >> 16], 1);
    }
    for (; j < s1; j += 512)
      atomicAdd(&dl[((unsigned)tmp[j]) >> 16], 1);
  }
  __syncthreads();
  int dv = dl[t], orig = dv;
#pragma unroll
  for (int o = 1; o < 64; o <<= 1) {
    int u = __shfl_up(dv, o, 64);
    if (lane >= o) dv += u;
  }
  if (lane == 63) ws[w] = dv;
  __syncthreads();
  if (t == 0) {
    int a = 0;
#pragma unroll
    for (int k = 0; k < 8; ++k) { int x = ws[k]; ws[k] = a; a += x; }
  }
  __syncthreads();
  int ex = ws[w] + dv - orig;
  cl[t] = ex;
  int node = (b << BSH) + t;
  float di = rsqrtf((float)(orig + 1));  // +1 self loop
  sdi[t] = di;
  if (node < n) {
    rowptr[node] = s0 + ex;
    dinv[node] = di;
  }
  if (b == kb - 1 && t == 0) rowptr[n] = e;
  __syncthreads();
  // pass 2: cursor scatter, 8 loads in flight
  {
    int j = s0 + t;
    for (; j < s1 - 3584; j += 4096) {
      int p0 = tmp[j];
      int p1 = tmp[j + 512];
      int p2 = tmp[j + 1024];
      int p3 = tmp[j + 1536];
      int p4 = tmp[j + 2048];
      int p5 = tmp[j + 2560];
      int p6 = tmp[j + 3072];
      int p7 = tmp[j + 3584];
      int r0 = atomicAdd(&cl[((unsigned)p0) >> 16], 1);
      int r1 = atomicAdd(&cl[((unsigned)p1) >> 16], 1);
      int r2 = atomicAdd(&cl[((unsigned)p2) >> 16], 1);
      int r3 = atomicAdd(&cl[((unsigned)p3) >> 16], 1);
      int r4 = atomicAdd(&cl[((unsigned)p4) >> 16], 1);
      int r5 = atomicAdd(&cl[((unsigned)p5) >> 16], 1);
      int r6 = atomicAdd(&cl[((unsigned)p6) >> 16], 1);
      int r7 = atomicAdd(&cl[((unsigned)p7) >> 16], 1);
      colarr[s0 + r0] = (unsigned short)(p0 & 0xFFFF);
      colarr[s0 + r1] = (unsigned short)(p1 & 0xFFFF);
      colarr[s0 + r2] = (unsigned short)(p2 & 0xFFFF);
      colarr[s0 + r3] = (unsigned short)(p3 & 0xFFFF);
      colarr[s0 + r4] = (unsigned short)(p4 & 0xFFFF);
      colarr[s0 + r5] = (unsigned short)(p5 & 0xFFFF);
      colarr[s0 + r6] = (unsigned short)(p6 & 0xFFFF);
      colarr[s0 + r7] = (unsigned short)(p7 & 0xFFFF);
    }
    for (; j < s1; j += 512) {
      int p = tmp[j];
      int r = atomicAdd(&cl[((unsigned)p) >> 16], 1);
      colarr[s0 + r] = (unsigned short)(p & 0xFFFF);
    }
  }
  // fused gscale (was K4): scale this bucket's rows of g16 by dinv.
  // coalesced: 16 consecutive lanes = one 256B row.
  {
    int base = b << BSH;
    int rows = n - base;
    if (rows > BSZ) rows = BSZ;
    uint4* G = (uint4*)g16;
    for (int idx = t; idx < rows * 16; idx += 512) {
      int rl = idx >> 4;
      float dsc = sdi[rl];
      size_t gi = (size_t)(base + rl) * 16 + (idx & 15);
      uint4 u = G[gi];
      __half2* hp = (__half2*)&u;
#pragma unroll
      for (int k2 = 0; k2 < 4; ++k2) {
        float2 f = __half22float2(hp[k2]);
        hp[k2] = __floats2half2_rn(f.x * dsc, f.y * dsc);
      }
      G[gi] = u;
    }
  }
}

// f16-input GEMM: C16 = fp16(rowscale * X16 @ W), A fp16-exact, B f16 hi+lo.
__global__ __launch_bounds__(256) void k_gemm_f16(
    const __half* __restrict__ X16, const short* __restrict__ fragH,
    const short* __restrict__ fragL, const float* __restrict__ rowscale,
    __half* __restrict__ C16, int n) {
  int wid = threadIdx.x >> 6, lane = threadIdx.x & 63;
  int r0 = (blockIdx.x * 4 + wid) * 16;
  if (r0 >= n) return;
  int m = lane & 15, quad = lane >> 4;
  const uint4* Xr = (const uint4*)(X16 + (size_t)(r0 + m) * 128);
  f32x4 acc[8];
#pragma unroll
  for (int t = 0; t < 8; ++t) acc[t] = (f32x4)(0.f);
  const int4* FH = (const int4*)fragH;
  const int4* FL = (const int4*)fragL;
#pragma unroll
  for (int s = 0; s < 4; ++s) {
    uint4 av = Xr[quad + 4 * s];
    f16x8 a = *(const f16x8*)&av;
#pragma unroll
    for (int t = 0; t < 8; ++t) {
      int idx = (t * 4 + s) * 64 + lane;
      int4 bhv = FH[idx], blv = FL[idx];
      f16x8 bh = *(const f16x8*)&bhv;
      f16x8 bl = *(const f16x8*)&blv;
      acc[t] = __builtin_amdgcn_mfma_f32_16x16x32_f16(a, bh, acc[t], 0, 0, 0);
      acc[t] = __builtin_amdgcn_mfma_f32_16x16x32_f16(a, bl, acc[t], 0, 0, 0);
    }
  }
  float sc[4];
#pragma unroll
  for (int r = 0; r < 4; ++r)
    sc[r] = rowscale ? rowscale[r0 + quad * 4 + r] : 1.f;
#pragma unroll
  for (int t = 0; t < 8; ++t) {
#pragma unroll
    for (int r = 0; r < 4; ++r) {
      int row = r0 + quad * 4 + r;
      C16[(size_t)row * 128 + t * 16 + m] = __float2half(acc[t][r] * sc[r]);
    }
  }
}

// out16[i,:] = fp16(relu(dinv[i] * (g[i,:] + sum g[col[e],:]) + bias))
// R13 known-good monolithic gather: uint4 lanes, 4 edge subgroups, 4-deep
// unroll = 16 edges in flight. DO NOT slice (R6/R7/R14 all regressed).
__global__ __launch_bounds__(256) void k_agg_h(
    const __half2* __restrict__ g2, const float* __restrict__ dinv,
    const int* __restrict__ rowptr, const unsigned short* __restrict__ col,
    const float* __restrict__ bias, __half* __restrict__ out16, int n) {
  int i = blockIdx.x * 4 + (threadIdx.x >> 6);
  if (i >= n) return;
  int lane = threadIdx.x & 63;
  int sub = lane >> 4;
  int c8 = lane & 15;
  const uint4* G = (const uint4*)g2;
  float4 z = make_float4(0.f, 0.f, 0.f, 0.f);
  float4 lo0 = z, lo1 = z, lo2 = z, lo3 = z, hi0 = z, hi1 = z, hi2 = z, hi3 = z;
  if (sub == 0) acc8(G[(size_t)i * 16 + c8], lo0, hi0);  // self loop once
  int beg = rowptr[i], end = rowptr[i + 1];
  int j = beg;
  for (; j + 16 <= end; j += 16) {
    int s0 = __builtin_nontemporal_load(&col[j + sub]);
    int s1 = __builtin_nontemporal_load(&col[j + 4 + sub]);
    int s2 = __builtin_nontemporal_load(&col[j + 8 + sub]);
    int s3 = __builtin_nontemporal_load(&col[j + 12 + sub]);
    uint4 u0 = G[(size_t)s0 * 16 + c8];
    uint4 u1 = G[(size_t)s1 * 16 + c8];
    uint4 u2 = G[(size_t)s2 * 16 + c8];
    uint4 u3 = G[(size_t)s3 * 16 + c8];
    acc8(u0, lo0, hi0); acc8(u1, lo1, hi1);
    acc8(u2, lo2, hi2); acc8(u3, lo3, hi3);
  }
  for (; j + 4 <= end; j += 4) {
    int s0 = __builtin_nontemporal_load(&col[j + sub]);
    acc8(G[(size_t)s0 * 16 + c8], lo1, hi1);
  }
  int rem = end - j;
  if (sub < rem) {
    int s0 = __builtin_nontemporal_load(&col[j + sub]);
    acc8(G[(size_t)s0 * 16 + c8], lo2, hi2);
  }
  float4 lo, hi;
  lo.x = (lo0.x + lo1.x) + (lo2.x + lo3.x);
  lo.y = (lo0.y + lo1.y) + (lo2.y + lo3.y);
  lo.z = (lo0.z + lo1.z) + (lo2.z + lo3.z);
  lo.w = (lo0.w + lo1.w) + (lo2.w + lo3.w);
  hi.x = (hi0.x + hi1.x) + (hi2.x + hi3.x);
  hi.y = (hi0.y + hi1.y) + (hi2.y + hi3.y);
  hi.z = (hi0.z + hi1.z) + (hi2.z + hi3.z);
  hi.w = (hi0.w + hi1.w) + (hi2.w + hi3.w);
  lo.x += __shfl_down(lo.x, 32, 64); lo.x += __shfl_down(lo.x, 16, 64);
  lo.y += __shfl_down(lo.y, 32, 64); lo.y += __shfl_down(lo.y, 16, 64);
  lo.z += __shfl_down(lo.z, 32, 64); lo.z += __shfl_down(lo.z, 16, 64);
  lo.w += __shfl_down(lo.w, 32, 64); lo.w += __shfl_down(lo.w, 16, 64);
  hi.x += __shfl_down(hi.x, 32, 64); hi.x += __shfl_down(hi.x, 16, 64);
  hi.y += __shfl_down(hi.y, 32, 64); hi.y += __shfl_down(hi.y, 16, 64);
  hi.z += __shfl_down(hi.z, 32, 64); hi.z += __shfl_down(hi.z, 16, 64);
  hi.w += __shfl_down(hi.w, 32, 64); hi.w += __shfl_down(hi.w, 16, 64);
  if (sub == 0) {
    float di = dinv[i];
    float4 b0 = ((const float4*)bias)[2 * c8];
    float4 b1 = ((const float4*)bias)[2 * c8 + 1];
    __half2 q0 = __floats2half2_rn(fmaxf(fmaf(di, lo.x, b0.x), 0.f),
                                   fmaxf(fmaf(di, lo.y, b0.y), 0.f));
    __half2 q1 = __floats2half2_rn(fmaxf(fmaf(di, lo.z, b0.z), 0.f),
                                   fmaxf(fmaf(di, lo.w, b0.w), 0.f));
    __half2 q2 = __floats2half2_rn(fmaxf(fmaf(di, hi.x, b1.x), 0.f),
                                   fmaxf(fmaf(di, hi.y, b1.y), 0.f));
    __half2 q3 = __floats2half2_rn(fmaxf(fmaf(di, hi.z, b1.z), 0.f),
                                   fmaxf(fmaf(di, hi.w, b1.w), 0.f));
    uint4 o;
    o.x = *(unsigned*)&q0; o.y = *(unsigned*)&q1;
    o.z = *(unsigned*)&q2; o.w = *(unsigned*)&q3;
    ((uint4*)out16)[(size_t)i * 16 + c8] = o;
  }
}

// R20: fused head. 16 pairs per wave; h2[i],h2[j] gathered directly as MFMA
// A-frags (lane m = pair p0+m, quad q = k-chunk q*8); Wh1a/b hi+lo frag
// tables staged in LDS (128KB, 1 block/CU, 16 waves = 4/SIMD).
// hidden = relu(h2i@Wh1a + h2j@Wh1b + bh1); out = hidden . Wh2 + bh2.
__global__ __launch_bounds__(1024) void k_pairs_mfma(
    const __half* __restrict__ h2,
    const short* __restrict__ fHa, const short* __restrict__ fLa,
    const short* __restrict__ fHb, const short* __restrict__ fLb,
    const int* __restrict__ pairs, const float* __restrict__ bh1,
    const float* __restrict__ wh2, const float* __restrict__ bh2,
    float* __restrict__ out, int P) {
  __shared__ int4 sF[4][2048];  // Ha, La, Hb, Lb = 128KB
  {
    const int4* g0 = (const int4*)fHa;
    const int4* g1 = (const int4*)fLa;
    const int4* g2 = (const int4*)fHb;
    const int4* g3 = (const int4*)fLb;
    for (int t = threadIdx.x; t < 2048; t += 1024) {
      sF[0][t] = g0[t];
      sF[1][t] = g1[t];
      sF[2][t] = g2[t];
      sF[3][t] = g3[t];
    }
  }
  __syncthreads();
  int w = threadIdx.x >> 6, lane = threadIdx.x & 63;
  int m = lane & 15, quad = lane >> 4;
  int p0 = blockIdx.x * 256 + w * 16;
  int pm = p0 + m;
  int iA = 0, jB = 0;
  if (pm < P) {
    iA = pairs[2 * pm];
    jB = pairs[2 * pm + 1];
  }
  const __half* ri = h2 + (size_t)iA * 128 + quad * 8;
  const __half* rj = h2 + (size_t)jB * 128 + quad * 8;
  f16x8 ai[4], aj[4];
#pragma unroll
  for (int s = 0; s < 4; ++s) {
    ai[s] = *(const f16x8*)(ri + s * 32);
    aj[s] = *(const f16x8*)(rj + s * 32);
  }
  f32x4 acc[8];
#pragma unroll
  for (int t = 0; t < 8; ++t) acc[t] = (f32x4)(0.f);
#pragma unroll
  for (int s = 0; s < 4; ++s) {
#pragma unroll
    for (int t = 0; t < 8; ++t) {
      int idx = (t * 4 + s) * 64 + lane;
      int4 vha = sF[0][idx], vla = sF[1][idx];
      int4 vhb = sF[2][idx], vlb = sF[3][idx];
      acc[t] = __builtin_amdgcn_mfma_f32_16x16x32_f16(ai[s], *(const f16x8*)&vha, acc[t], 0, 0, 0);
      acc[t] = __builtin_amdgcn_mfma_f32_16x16x32_f16(ai[s], *(const f16x8*)&vla, acc[t], 0, 0, 0);
      acc[t] = __builtin_amdgcn_mfma_f32_16x16x32_f16(aj[s], *(const f16x8*)&vhb, acc[t], 0, 0, 0);
      acc[t] = __builtin_amdgcn_mfma_f32_16x16x32_f16(aj[s], *(const f16x8*)&vlb, acc[t], 0, 0, 0);
    }
  }
  float sP[4] = {0.f, 0.f, 0.f, 0.f};
#pragma unroll
  for (int t = 0; t < 8; ++t) {
    float bb = bh1[t * 16 + m];
    float ww = wh2[t * 16 + m];
#pragma unroll
    for (int r = 0; r < 4; ++r)
      sP[r] += fmaxf(acc[t][r] + bb, 0.f) * ww;
  }
#pragma unroll
  for (int o = 8; o > 0; o >>= 1) {
#pragma unroll
    for (int r = 0; r < 4; ++r) sP[r] += __shfl_down(sP[r], o, 64);
  }
  if (m == 0) {
    float bb2 = bh2[0];
#pragma unroll
    for (int r = 0; r < 4; ++r) {
      int p = p0 + quad * 4 + r;
      if (p < P) out[p] = sP[r] + bb2;
    }
  }
}

extern "C" void kernel_launch(void* const* d_in, const int* in_sizes, int n_in,
                              void* d_out, int out_size, void* d_ws, size_t ws_size,
                              hipStream_t stream) {
  const float* x   = (const float*)d_in[0];
  const int* ei    = (const int*)d_in[1];
  const int* pairs = (const int*)d_in[2];
  const float* W1  = (const float*)d_in[3];
  const float* b1  = (const float*)d_in[4];
  const float* W2  = (const float*)d_in[5];
  const float* b2  = (const float*)d_in[6];
  const float* Wh1 = (const float*)d_in[7];
  const float* bh1 = (const float*)d_in[8];
  const float* Wh2 = (const float*)d_in[9];
  const float* bh2 = (const float*)d_in[10];
  (void)n_in; (void)out_size; (void)ws_size;

  int N = in_sizes[0] / 128;
  int E = in_sizes[1] / 2;
  int P = in_sizes[2] / 2;
  const int* src = ei;
  const int* dst = ei + E;
  int KB = (N + BSZ - 1) >> BSH;  // buckets (98 for N=50000)

  char* wsp = (char*)d_ws;
  size_t off = 0;
  auto alloc = [&](size_t bytes) -> void* {
    void* p = wsp + off;
    off += (bytes + 255) & ~(size_t)255;
    return p;
  };
  __half* g16 = (__half*)alloc((size_t)N * 128 * 2);  // messages
  __half* h1  = (__half*)alloc((size_t)N * 128 * 2);  // fp16
  __half* h2  = (__half*)alloc((size_t)N * 128 * 2);  // fp16
  float* dinv = (float*)alloc((size_t)N * 4);
  int* rowptr = (int*)alloc((size_t)(N + 1) * 4);
  unsigned short* colarr = (unsigned short*)alloc((size_t)E * 2);
  int* tmp    = (int*)alloc((size_t)E * 4);
  short* fragH = (short*)alloc(4 * 2048 * 8 * 2);     // 128KB
  short* fragL = (short*)alloc(4 * 2048 * 8 * 2);     // 128KB
  int* gc     = (int*)alloc(2 * 128 * 4);             // [0:128) gcnt, [128:256) gcur
  int* gcnt = gc;
  int* gcur = gc + 128;
  short* fH_W1 = fragH + 0 * 16384;  short* fL_W1 = fragL + 0 * 16384;
  short* fH_W2 = fragH + 1 * 16384;  short* fL_W2 = fragL + 1 * 16384;
  short* fH_Wa = fragH + 2 * 16384;  short* fL_Wa = fragL + 2 * 16384;
  short* fH_Wb = fragH + 3 * 16384;  short* fL_Wb = fragL + 3 * 16384;

  int GB = (N + 63) / 64;          // gemm1: 64 rows per block
  int GF = (N / 16 + 3) / 4;       // f16 gemm: 16 rows/wave, 4 waves/block
  int AB = (N + 3) / 4;            // agg: 4 rows per block
  int MS = (E + MSB - 1) / MSB;    // multisplit blocks

  // one memset for both counter arrays, then fused prep+hist
  hipMemsetAsync(gc, 0, 2 * 128 * 4, stream);
  k_prep_hist<<<32 + HB, 256, 0, stream>>>(W1, W2, Wh1, fragH, fragL,
                                           dst, gcnt, E, KB);
  // K2: multisplit UNION gemm1 (raw, unscaled)
  k_ms_gemm1<<<MS + GB, 256, 0, stream>>>(src, dst, gcnt, gcur, tmp, E, KB, MS,
                                          x, fH_W1, fL_W1, g16, N);
  // K3: per-bucket LDS sort -> rowptr/dinv/colarr, then fused g16 row-scale
  k_bucket_build<<<KB, 512, 0, stream>>>(tmp, gcnt, rowptr, dinv, colarr,
                                         g16, N, KB, E);
  // conv1 agg
  k_agg_h<<<AB, 256, 0, stream>>>((const __half2*)g16, dinv, rowptr, colarr, b1, h1, N);
  // conv2 (f16 path)
  k_gemm_f16<<<GF, 256, 0, stream>>>(h1, fH_W2, fL_W2, dinv, g16, N);
  k_agg_h<<<AB, 256, 0, stream>>>((const __half2*)g16, dinv, rowptr, colarr, b2, h2, N);
  // head: fused dual-gemm + pairs (R20)
  k_pairs_mfma<<<(P + 255) / 256, 1024, 0, stream>>>(
      h2, fH_Wa, fL_Wa, fH_Wb, fL_Wb, pairs, bh1, Wh2, bh2,
      (float*)d_out, P);
}